// Round 8
// baseline (21457.318 us; speedup 1.0000x reference)
//
#include <hip/hip_runtime.h>
#include <math.h>

#define VOCAB 32000
#define EMBD  512
#define HID   1024
#define BATCH 32
#define SEQ   64
#define TENC  64
#define NSTEP 63
#define G4    4096
#define NB    128          // persistent grid: 128 blocks (<=256 CUs, all resident)
#define NT    512

__device__ __forceinline__ float4 ld4(const float* p) {
  return *reinterpret_cast<const float4*>(p);
}

struct LoopP {
  const int* tgt; const float* emb;
  const float* Wih0; const float* Whh0; const float* Wih1; const float* Whh1;
  const float* Wa; const float* Wc; const float* va; const float* bc;
  const float* bsum0; const float* bsum1;
  const float* PreAC; const float* Gemb; const float* zbuf;
  float* h0A; float* h0B; float* h1A; float* h1B;
  float* c0; float* c1;
  float* Pq; float* AH;
  unsigned* bars;
};

// ---- two-level grid barrier: groups of 16 (XCD-aligned via bid&7), 8 leaders ----
// bars layout (unsigned): gcnt[grp] @ grp*32 ; ggen[grp] @ 256+grp*32 ;
//                         mcnt @ 512 ; mgen @ 544   (all on separate 128B lines)
__device__ __forceinline__ void gbar(unsigned* bars, unsigned* pgen) {
  __syncthreads();
  if (threadIdx.x == 0) {
    const unsigned g = *pgen;
    __threadfence();
    const int grp = blockIdx.x & 7;
    unsigned* gcnt = bars + grp * 32;
    unsigned* ggen = bars + 256 + grp * 32;
    unsigned* mcnt = bars + 512;
    unsigned* mgen = bars + 544;
    const unsigned old = __hip_atomic_fetch_add(gcnt, 1u, __ATOMIC_ACQ_REL, __HIP_MEMORY_SCOPE_AGENT);
    if ((old & 15u) == 15u) {                 // last of the 16 in this group
      const unsigned mo = __hip_atomic_fetch_add(mcnt, 1u, __ATOMIC_ACQ_REL, __HIP_MEMORY_SCOPE_AGENT);
      if ((mo & 7u) == 7u) {
        __hip_atomic_store(mgen, g + 1u, __ATOMIC_RELEASE, __HIP_MEMORY_SCOPE_AGENT);
      } else {
        while (__hip_atomic_load(mgen, __ATOMIC_ACQUIRE, __HIP_MEMORY_SCOPE_AGENT) == g)
          __builtin_amdgcn_s_sleep(2);
      }
      __hip_atomic_store(ggen, g + 1u, __ATOMIC_RELEASE, __HIP_MEMORY_SCOPE_AGENT);
    } else {
      while (__hip_atomic_load(ggen, __ATOMIC_ACQUIRE, __HIP_MEMORY_SCOPE_AGENT) == g)
        __builtin_amdgcn_s_sleep(2);
    }
    *pgen = g + 1u;
  }
  __syncthreads();
}

// ---- gates phase loaders ----
template<int MODE, int HOIST>   // MODE 0: layer0, 1: layer1
__device__ __forceinline__ float4 gA(const LoopP& P, const float* sA, const float* sB,
                                     int b, int k, int t) {
  if (MODE == 0 && !HOIST) {
    if (k < EMBD) {
      const int tok = P.tgt[b * SEQ + t];
      return ld4(P.emb + (size_t)tok * EMBD + k);
    }
    k -= EMBD;
  }
  if (k < HID) return ld4(sA + b * HID + k);
  return ld4(sB + b * HID + (k - HID));
}

template<int MODE, int HOIST>
__device__ __forceinline__ float4 gW(const LoopP& P, int row, int k) {
  if (MODE == 0) {
    if (HOIST) {
      if (k < HID) return ld4(P.Wih0 + (size_t)row * (EMBD + HID) + EMBD + k);
      return ld4(P.Whh0 + (size_t)row * HID + (k - HID));
    } else {
      if (k < EMBD + HID) return ld4(P.Wih0 + (size_t)row * (EMBD + HID) + k);
      return ld4(P.Whh0 + (size_t)row * HID + (k - EMBD - HID));
    }
  } else {
    if (k < HID) return ld4(P.Wih1 + (size_t)row * HID + k);
    return ld4(P.Whh1 + (size_t)row * HID + (k - HID));
  }
}

// gates GEMM (32 rows = 4 gates x 8 n, 32 b) + block-local LSTM cell.
// Two 256-thread teams K-split the 2048(2560) dot; LDS-reduce; cell by tid<256.
template<int MODE, int HOIST>
__device__ void gphase(const LoopP& P, float* lds, int t,
                       const float* sA, const float* sB,
                       const float* bsum, const float* gembt,
                       float* h_new, float* c) {
  const int tid = threadIdx.x;
  const int ttid = tid & 255, team = tid >> 8;
  const int lr = ttid >> 3, lc = (ttid & 7) << 2;
  const int tn = ttid & 15, tm = ttid >> 4;
  const int n0 = blockIdx.x * 8;
  const int wrow = (lr >> 3) * 1024 + n0 + (lr & 7);
  const int K  = (MODE == 0 && !HOIST) ? 2560 : 2048;
  const int CH = K >> 1;
  const int kbeg = team * CH;
  float* At = lds + team * 2176;
  float* Wt = At + 1088;
  float a00=0.f, a01=0.f, a10=0.f, a11=0.f;
  float4 av = gA<MODE,HOIST>(P, sA, sB, lr, kbeg + lc, t);
  float4 wv = gW<MODE,HOIST>(P, wrow, kbeg + lc);
  for (int k0 = kbeg; k0 < kbeg + CH; k0 += 32) {
    float4 avn, wvn;
    if (k0 + 32 < kbeg + CH) {
      avn = gA<MODE,HOIST>(P, sA, sB, lr, k0 + 32 + lc, t);
      wvn = gW<MODE,HOIST>(P, wrow, k0 + 32 + lc);
    }
    __syncthreads();
    At[(lc+0)*34+lr]=av.x; At[(lc+1)*34+lr]=av.y; At[(lc+2)*34+lr]=av.z; At[(lc+3)*34+lr]=av.w;
    Wt[(lc+0)*34+lr]=wv.x; Wt[(lc+1)*34+lr]=wv.y; Wt[(lc+2)*34+lr]=wv.z; Wt[(lc+3)*34+lr]=wv.w;
    __syncthreads();
    #pragma unroll
    for (int kk = 0; kk < 32; ++kk) {
      const float2 a = *reinterpret_cast<const float2*>(&At[kk*34 + tm*2]);
      const float2 w = *reinterpret_cast<const float2*>(&Wt[kk*34 + tn*2]);
      a00 += a.x*w.x; a01 += a.x*w.y; a10 += a.y*w.x; a11 += a.y*w.y;
    }
    av = avn; wv = wvn;
  }
  __syncthreads();                       // all teams done reading tiles
  float* res = lds + team * 2176;        // [32 b][32 r] per team
  res[(tm*2  )*32 + tn*2  ] = a00;
  res[(tm*2  )*32 + tn*2+1] = a01;
  res[(tm*2+1)*32 + tn*2  ] = a10;
  res[(tm*2+1)*32 + tn*2+1] = a11;
  __syncthreads();
  if (tid < 256) {                       // 32 b x 8 n cells, block-local
    const int b = tid >> 3, j = tid & 7;
    float g4v[4];
    #pragma unroll
    for (int g = 0; g < 4; ++g) {
      const int r = g*8 + j;
      float s = lds[b*32 + r] + lds[2176 + b*32 + r] + bsum[g*1024 + n0 + j];
      if (MODE == 0 && HOIST) s += gembt[(size_t)b*G4 + g*1024 + n0 + j];
      g4v[g] = s;
    }
    const float si = 1.f/(1.f+expf(-g4v[0]));
    const float sf = 1.f/(1.f+expf(-g4v[1]));
    const float so = 1.f/(1.f+expf(-g4v[3]));
    const int i = b*HID + n0 + j;
    const float cn = sf*c[i] + si*tanhf(g4v[2]);
    c[i] = cn;
    h_new[i] = so*tanhf(cn);
  }
}

// proj: Pq[sp][32][2048] = h1_new x [Wa1;Wc1]^T, 64 tiles x 4 K-splits = 256 teams
__device__ void projphase(const LoopP& P, float* lds, const float* h1n) {
  const int tid = threadIdx.x;
  const int ttid = tid & 255, team = tid >> 8;
  const int gt = blockIdx.x * 2 + team;
  const int nt = gt & 63, sp = gt >> 6;
  const int lr = ttid >> 3, lc = (ttid & 7) << 2;
  const int tn = ttid & 15, tm = ttid >> 4;
  const int kbeg = sp * 256;
  const int row = nt*32 + lr;
  const float* wb = (row < HID) ? (P.Wa + (size_t)row * (2*HID))
                                : (P.Wc + (size_t)(row - HID) * (2*HID));
  float* At = lds + team * 2176;
  float* Wt = At + 1088;
  float a00=0.f, a01=0.f, a10=0.f, a11=0.f;
  float4 av = ld4(h1n + lr*HID + kbeg + lc);
  float4 wv = ld4(wb + kbeg + lc);
  for (int k0 = kbeg; k0 < kbeg + 256; k0 += 32) {
    float4 avn, wvn;
    if (k0 + 32 < kbeg + 256) {
      avn = ld4(h1n + lr*HID + k0 + 32 + lc);
      wvn = ld4(wb + k0 + 32 + lc);
    }
    __syncthreads();
    At[(lc+0)*34+lr]=av.x; At[(lc+1)*34+lr]=av.y; At[(lc+2)*34+lr]=av.z; At[(lc+3)*34+lr]=av.w;
    Wt[(lc+0)*34+lr]=wv.x; Wt[(lc+1)*34+lr]=wv.y; Wt[(lc+2)*34+lr]=wv.z; Wt[(lc+3)*34+lr]=wv.w;
    __syncthreads();
    #pragma unroll
    for (int kk = 0; kk < 32; ++kk) {
      const float2 a = *reinterpret_cast<const float2*>(&At[kk*34 + tm*2]);
      const float2 w = *reinterpret_cast<const float2*>(&Wt[kk*34 + tn*2]);
      a00 += a.x*w.x; a01 += a.x*w.y; a10 += a.y*w.x; a11 += a.y*w.y;
    }
    av = avn; wv = wvn;
  }
  const int na = nt*32 + tn*2, ma = tm*2;
  P.Pq[((size_t)sp*BATCH + ma  )*2048 + na  ] = a00;
  P.Pq[((size_t)sp*BATCH + ma  )*2048 + na+1] = a01;
  P.Pq[((size_t)sp*BATCH + ma+1)*2048 + na  ] = a10;
  P.Pq[((size_t)sp*BATCH + ma+1)*2048 + na+1] = a11;
}

// attn: blocks 0..31 (per batch), q-sum + scores + softmax + context + attn_h
__device__ void attnphase(const LoopP& P, float* lds, int t) {
  const int b = blockIdx.x;
  if (b >= BATCH) return;
  const int tid = threadIdx.x;
  float* QS  = lds;
  float* sw  = lds + 1024;
  float* W64 = lds + 1088;
  for (int idx = tid; idx < HID; idx += NT) {
    float s = 0.f;
    #pragma unroll
    for (int sp = 0; sp < 4; ++sp) s += P.Pq[((size_t)sp*BATCH + b)*2048 + idx];
    QS[idx] = s;
  }
  __syncthreads();
  const int lane = tid & 63, wid = tid >> 6;   // 8 waves
  float vreg[16];
  #pragma unroll
  for (int i2 = 0; i2 < 16; ++i2) vreg[i2] = P.va[lane + 64*i2];
  #pragma unroll
  for (int j = 0; j < 8; ++j) {
    const int te = wid*8 + j;
    const float* pr = P.PreAC + ((size_t)te*BATCH + b)*2048;
    float s = 0.f;
    #pragma unroll
    for (int i2 = 0; i2 < 16; ++i2) {
      const int idx = lane + 64*i2;
      s += vreg[i2] * tanhf(QS[idx] + pr[idx]);
    }
    for (int off = 32; off; off >>= 1) s += __shfl_xor(s, off);
    if (lane == 0) sw[te] = s;
  }
  __syncthreads();
  if (tid < TENC) {
    const float v = sw[tid];
    float mx = v;
    for (int off = 32; off; off >>= 1) mx = fmaxf(mx, __shfl_xor(mx, off));
    const float e = expf(v - mx);
    float sum = e;
    for (int off = 32; off; off >>= 1) sum += __shfl_xor(sum, off);
    W64[tid] = e / sum;
  }
  __syncthreads();
  #pragma unroll
  for (int q = 0; q < 2; ++q) {
    const int hh = q*NT + tid;
    float acc = 0.f;
    #pragma unroll 8
    for (int te = 0; te < TENC; ++te)
      acc += W64[te] * P.PreAC[((size_t)te*BATCH + b)*2048 + HID + hh];
    float hc = P.bc[hh];
    #pragma unroll
    for (int sp = 0; sp < 4; ++sp) hc += P.Pq[((size_t)sp*BATCH + b)*2048 + HID + hh];
    P.AH[((size_t)t*BATCH + b)*HID + hh] = tanhf(acc + hc);
  }
}

template<int HOIST>
__global__ __launch_bounds__(NT, 1) void loop_k(LoopP P) {
  __shared__ float lds[4352];
  unsigned gen = 0;
  for (int t = 0; t < NSTEP; ++t) {
    const int cur = t & 1;
    const float* ahp = t ? (P.AH + (size_t)(t-1)*BATCH*HID) : P.zbuf;
    const float* h0r = cur ? P.h0B : P.h0A;
    float*       h0w = cur ? P.h0A : P.h0B;
    const float* h1r = cur ? P.h1B : P.h1A;
    float*       h1w = cur ? P.h1A : P.h1B;
    gphase<0,HOIST>(P, lds, t, ahp, h0r, P.bsum0,
                    HOIST ? (P.Gemb + (size_t)t*BATCH*G4) : (const float*)nullptr,
                    h0w, P.c0);
    gbar(P.bars, &gen);
    gphase<1,HOIST>(P, lds, t, h0w, h1r, P.bsum1, nullptr, h1w, P.c1);
    gbar(P.bars, &gen);
    projphase(P, lds, h1w);
    gbar(P.bars, &gen);
    attnphase(P, lds, t);
    gbar(P.bars, &gen);
  }
}

// ============ wide GEMM, 32m x 256n tiles, 4x8/thread, prefetched ============
// WM 0: logits C[2016x32000] = AH*Wo^T + bo             (K=1024)
// WM 1: PreAC  C[2048x2048]  = enc*[Wa2;Wc2]^T + [ba;0] (K=1024)
// WM 2: Gemb   C[2016x4096]  = emb[tok]*Wih0[:,:512]^T  (K=512, gathered A)
struct WGP {
  const float* A; const float* W; const float* W2; const float* bias;
  const int* tgt; const float* emb;
  float* C; int ldc;
};

template<int WM>
__device__ __forceinline__ float4 ldWL(const WGP& P, int r, int k) {
  if (WM == 0) return ld4(P.W + (size_t)r * 1024 + k);
  if (WM == 2) return ld4(P.W + (size_t)r * (EMBD + HID) + k);
  if (r < HID) return ld4(P.W  + (size_t)r * (2*HID) + HID + k);
  return ld4(P.W2 + (size_t)(r - HID) * (2*HID) + HID + k);
}

template<int WM>
__device__ __forceinline__ float4 ldAL(const WGP& P, int row, int k) {
  if (WM == 2) {
    const int tok = P.tgt[(row & 31) * SEQ + (row >> 5)];
    return ld4(P.emb + (size_t)tok * EMBD + k);
  }
  return ld4(P.A + (size_t)row * 1024 + k);
}

template<int WM>
__global__ __launch_bounds__(256, 2) void gemmL(WGP P) {
  constexpr int KK = (WM == 2) ? 512 : 1024;
  __shared__ float At[32*36];
  __shared__ float Wt[32*260];
  const int tid = threadIdx.x;
  const int m0 = blockIdx.x * 32;
  const int n0 = blockIdx.y * 256;
  const int lr = tid >> 3, lc = (tid & 7) << 2;
  const int tn = tid & 31, tm = tid >> 5;
  float acc[4][8];
  #pragma unroll
  for (int i = 0; i < 4; ++i)
    #pragma unroll
    for (int x = 0; x < 8; ++x) acc[i][x] = 0.f;

  float4 av = ldAL<WM>(P, m0 + lr, lc);
  float4 wv[8];
  #pragma unroll
  for (int it = 0; it < 8; ++it) wv[it] = ldWL<WM>(P, n0 + lr + it*32, lc);

  for (int k0 = 0; k0 < KK; k0 += 32) {
    float4 avn, wvn[8];
    if (k0 + 32 < KK) {
      avn = ldAL<WM>(P, m0 + lr, k0 + 32 + lc);
      #pragma unroll
      for (int it = 0; it < 8; ++it) wvn[it] = ldWL<WM>(P, n0 + lr + it*32, k0 + 32 + lc);
    }
    __syncthreads();
    At[(lc+0)*36+lr]=av.x; At[(lc+1)*36+lr]=av.y; At[(lc+2)*36+lr]=av.z; At[(lc+3)*36+lr]=av.w;
    #pragma unroll
    for (int it = 0; it < 8; ++it) {
      const int r = lr + it*32;
      Wt[(lc+0)*260+r]=wv[it].x; Wt[(lc+1)*260+r]=wv[it].y;
      Wt[(lc+2)*260+r]=wv[it].z; Wt[(lc+3)*260+r]=wv[it].w;
    }
    __syncthreads();
    #pragma unroll
    for (int kk = 0; kk < 32; ++kk) {
      const float4 a  = *reinterpret_cast<const float4*>(&At[kk*36 + tm*4]);
      const float4 w0 = *reinterpret_cast<const float4*>(&Wt[kk*260 + tn*8]);
      const float4 w1 = *reinterpret_cast<const float4*>(&Wt[kk*260 + tn*8 + 4]);
      #pragma unroll
      for (int i = 0; i < 4; ++i) {
        const float ai = (&a.x)[i];
        acc[i][0]+=ai*w0.x; acc[i][1]+=ai*w0.y; acc[i][2]+=ai*w0.z; acc[i][3]+=ai*w0.w;
        acc[i][4]+=ai*w1.x; acc[i][5]+=ai*w1.y; acc[i][6]+=ai*w1.z; acc[i][7]+=ai*w1.w;
      }
    }
    av = avn;
    #pragma unroll
    for (int it = 0; it < 8; ++it) wv[it] = wvn[it];
  }
  const int na = n0 + tn*8, ma = m0 + tm*4;
  float bb[8];
  #pragma unroll
  for (int x = 0; x < 8; ++x) {
    if (WM == 0)      bb[x] = P.bias[na+x];
    else if (WM == 1) bb[x] = (na + x < HID) ? P.bias[na+x] : 0.f;
    else              bb[x] = 0.f;
  }
  #pragma unroll
  for (int i = 0; i < 4; ++i)
    #pragma unroll
    for (int x = 0; x < 8; ++x)
      P.C[(size_t)(ma+i)*P.ldc + na + x] = acc[i][x] + bb[x];
}

// per-(b,t): logits row -> log-softmax in place + argmax word
__global__ __launch_bounds__(256) void lsm_k(float* __restrict__ out,
                                             float* __restrict__ words) {
  const int b = blockIdx.x;
  const int t = blockIdx.y;
  float* row = out + ((size_t)t*BATCH + b)*VOCAB;
  const int tid = threadIdx.x;
  float m = -INFINITY; int mi = 0;
  for (int v = tid; v < VOCAB; v += 256) {
    const float x = row[v];
    if (x > m) { m = x; mi = v; }
  }
  __shared__ float sm[256]; __shared__ int si[256];
  sm[tid] = m; si[tid] = mi;
  __syncthreads();
  for (int s2 = 128; s2; s2 >>= 1) {
    if (tid < s2) {
      const float om = sm[tid+s2]; const int oi = si[tid+s2];
      if (om > sm[tid] || (om == sm[tid] && oi < si[tid])) { sm[tid]=om; si[tid]=oi; }
    }
    __syncthreads();
  }
  const float mx = sm[0]; const int amax = si[0];
  float s = 0.f;
  for (int v = tid; v < VOCAB; v += 256) s += expf(row[v]-mx);
  __shared__ float ss[256];
  ss[tid] = s; __syncthreads();
  for (int s2=128; s2; s2>>=1) { if (tid < s2) ss[tid] += ss[tid+s2]; __syncthreads(); }
  const float lse = logf(ss[0]) + mx;
  for (int v = tid; v < VOCAB; v += 256) row[v] = row[v] - lse;
  if (tid == 0) words[(size_t)t*BATCH + b] = (float)amax;
}

__global__ __launch_bounds__(256) void init_k(const float* __restrict__ enc_h,
                                              const float* __restrict__ enc_c,
                                              const float* __restrict__ bih0,
                                              const float* __restrict__ bhh0,
                                              const float* __restrict__ bih1,
                                              const float* __restrict__ bhh1,
                                              float* h0, float* h1, float* c0,
                                              float* c1, float* zbuf,
                                              float* bsum0, float* bsum1,
                                              unsigned* bars) {
  const int i = blockIdx.x*256 + threadIdx.x;
  if (i < BATCH*HID) {
    h0[i] = enc_h[i]; h1[i] = enc_h[BATCH*HID + i];
    c0[i] = enc_c[i]; c1[i] = enc_c[BATCH*HID + i];
    zbuf[i] = 0.f;
  }
  if (i < G4) {
    bsum0[i] = bih0[i] + bhh0[i];
    bsum1[i] = bih1[i] + bhh1[i];
  }
  if (i < 1024) bars[i] = 0u;
}

extern "C" void kernel_launch(void* const* d_in, const int* in_sizes, int n_in,
                              void* d_out, int out_size, void* d_ws, size_t ws_size,
                              hipStream_t stream) {
  const int*   tgt   = (const int*)d_in[0];
  const float* enc_h = (const float*)d_in[1];
  const float* enc_c = (const float*)d_in[2];
  const float* enc   = (const float*)d_in[3];
  const float* emb   = (const float*)d_in[4];
  const float* Wih0  = (const float*)d_in[5];
  const float* Whh0  = (const float*)d_in[6];
  const float* bih0  = (const float*)d_in[7];
  const float* bhh0  = (const float*)d_in[8];
  const float* Wih1  = (const float*)d_in[9];
  const float* Whh1  = (const float*)d_in[10];
  const float* bih1  = (const float*)d_in[11];
  const float* bhh1  = (const float*)d_in[12];
  const float* Wa    = (const float*)d_in[13];
  const float* ba    = (const float*)d_in[14];
  const float* va    = (const float*)d_in[15];
  const float* Wc    = (const float*)d_in[16];
  const float* bc    = (const float*)d_in[17];
  const float* Wo    = (const float*)d_in[18];
  const float* bo    = (const float*)d_in[19];

  float* ws    = (float*)d_ws;
  float* PreAC = ws;                                    // [2048,2048]
  float* AH    = PreAC + (size_t)2048*2048;             // [63,32,1024]
  float* Pq    = AH    + (size_t)NSTEP*BATCH*HID;       // [4,32,2048]
  float* h0A   = Pq    + (size_t)4*BATCH*2048;
  float* h0B   = h0A  + BATCH*HID;
  float* h1A   = h0B  + BATCH*HID;
  float* h1B   = h1A  + BATCH*HID;
  float* c0    = h1B  + BATCH*HID;
  float* c1v   = c0   + BATCH*HID;
  float* zbuf  = c1v  + BATCH*HID;
  float* bsum0 = zbuf + BATCH*HID;
  float* bsum1 = bsum0 + G4;
  unsigned* bars = (unsigned*)(bsum1 + G4);             // 1024 u32
  float* Gemb  = (float*)(bars + 1024);                 // [63,32,4096] optional
  const size_t base_f = (size_t)(Gemb - ws);
  const bool hoist = ws_size >= (base_f + (size_t)NSTEP*BATCH*G4) * sizeof(float);

  float* out   = (float*)d_out;
  float* words = out + (size_t)NSTEP*BATCH*VOCAB;

  init_k<<<dim3(128), 256, 0, stream>>>(enc_h, enc_c, bih0, bhh0, bih1, bhh1,
                                        h0A, h1A, c0, c1v, zbuf, bsum0, bsum1, bars);

  { // PreAC = enc @ [Wa2; Wc2]^T + [ba; 0]
    WGP p = {}; p.A = enc; p.W = Wa; p.W2 = Wc; p.bias = ba; p.C = PreAC; p.ldc = 2048;
    gemmL<1><<<dim3(64, 8), 256, 0, stream>>>(p);
  }
  if (hoist) { // Gemb = emb[tok] @ Wih0[:, :512]^T for all (t,b) upfront
    WGP p = {}; p.W = Wih0; p.tgt = tgt; p.emb = emb; p.C = Gemb; p.ldc = G4;
    gemmL<2><<<dim3(NSTEP*BATCH/32, G4/256), 256, 0, stream>>>(p);
  }

  { // persistent 63-step recurrence: one launch, 4 tree-barriers per step
    LoopP p;
    p.tgt = tgt; p.emb = emb;
    p.Wih0 = Wih0; p.Whh0 = Whh0; p.Wih1 = Wih1; p.Whh1 = Whh1;
    p.Wa = Wa; p.Wc = Wc; p.va = va; p.bc = bc;
    p.bsum0 = bsum0; p.bsum1 = bsum1;
    p.PreAC = PreAC; p.Gemb = Gemb; p.zbuf = zbuf;
    p.h0A = h0A; p.h0B = h0B; p.h1A = h1A; p.h1B = h1B;
    p.c0 = c0; p.c1 = c1v;
    p.Pq = Pq; p.AH = AH; p.bars = bars;
    if (hoist) loop_k<1><<<dim3(NB), NT, 0, stream>>>(p);
    else       loop_k<0><<<dim3(NB), NT, 0, stream>>>(p);
  }

  { // batched logits: [2016 x 32000], K=1024
    WGP p = {}; p.A = AH; p.W = Wo; p.bias = bo; p.C = out; p.ldc = VOCAB;
    gemmL<0><<<dim3(NSTEP*BATCH/32, VOCAB/256), 256, 0, stream>>>(p);
  }
  lsm_k<<<dim3(BATCH, NSTEP), 256, 0, stream>>>(out, words);
}

// Round 9
// 13020.311 us; speedup vs baseline: 1.6480x; 1.6480x over previous
//
#include <hip/hip_runtime.h>
#include <math.h>

#define VOCAB 32000
#define EMBD  512
#define HID   1024
#define BATCH 32
#define SEQ   64
#define TENC  64
#define NSTEP 63
#define G4    4096

typedef __attribute__((ext_vector_type(8))) short short8;
typedef __attribute__((ext_vector_type(4))) float f32x4;
typedef __attribute__((ext_vector_type(4))) unsigned short us4;

__device__ __forceinline__ float4 ld4(const float* p) {
  return *reinterpret_cast<const float4*>(p);
}
__device__ __forceinline__ unsigned short f2bf(float x) {
  unsigned u = __float_as_uint(x);
  return (unsigned short)((u + 0x7fffu + ((u >> 16) & 1u)) >> 16);
}
__device__ __forceinline__ float bf2f(unsigned short h) {
  return __uint_as_float(((unsigned)h) << 16);
}

// ---- shared 32x32-tile full-K GEMM core: C[32 b][32 wrows] += A·W^T ----
// Caller passes per-thread row pointers via lambdas fa(k)/fw(k) -> float4.
template<class FA, class FW>
__device__ __forceinline__ void g32(FA fa, FW fw, int K, float* At, float* Wt,
                                    float& a00, float& a01, float& a10, float& a11) {
  const int tid = threadIdx.x;
  const int lr = tid >> 3, lc = (tid & 7) << 2;
  const int tn = tid & 15, tm = tid >> 4;
  (void)lr;
  float4 av = fa(lc);
  float4 wv = fw(lc);
  for (int k0 = 0; k0 < K; k0 += 32) {
    float4 avn, wvn;
    if (k0 + 32 < K) { avn = fa(k0 + 32 + lc); wvn = fw(k0 + 32 + lc); }
    __syncthreads();
    At[(lc+0)*34+lr]=av.x; At[(lc+1)*34+lr]=av.y; At[(lc+2)*34+lr]=av.z; At[(lc+3)*34+lr]=av.w;
    Wt[(lc+0)*34+lr]=wv.x; Wt[(lc+1)*34+lr]=wv.y; Wt[(lc+2)*34+lr]=wv.z; Wt[(lc+3)*34+lr]=wv.w;
    __syncthreads();
    #pragma unroll
    for (int kk = 0; kk < 32; ++kk) {
      const float2 a = *reinterpret_cast<const float2*>(&At[kk*34 + tm*2]);
      const float2 w = *reinterpret_cast<const float2*>(&Wt[kk*34 + tn*2]);
      a00 += a.x*w.x; a01 += a.x*w.y; a10 += a.y*w.x; a11 += a.y*w.y;
    }
    av = avn; wv = wvn;
  }
}

// ========== gates GEMM (full K) + block-local LSTM cell ==========
// Block nt owns n-range [nt*8, nt*8+8) across all 4 gates (32 W-rows), 32 batches.
struct GC {
  const int* tgt; const float* emb;
  const float* A;        // L0: ah_prev ; L1: h0 (new)
  const float* W;        // Wih0 / Wih1
  const float* gembt;    // Gemb + t*32*4096 (L0 hoist) else unused
  const float* PgH;      // Whh·h_{t-1} (hoisted last step)
  const float* bsum;
  float* h; float* c; int t;
};

template<int LAYER, int HOIST>
__global__ __launch_bounds__(256) void gcell_k(GC P) {
  __shared__ float At[32*34], Wt[32*34], res[32*33];
  const int nt = blockIdx.x;
  const int tid = threadIdx.x;
  const int lr = tid >> 3;
  const int wrow = (lr >> 3)*1024 + nt*8 + (lr & 7);   // g*1024 + n
  float a00=0.f, a01=0.f, a10=0.f, a11=0.f;
  if (LAYER == 0) {
    const float* Wp = P.W + (size_t)wrow*(EMBD+HID) + (HOIST ? EMBD : 0);
    const float* Ap = P.A + lr*HID;
    if (HOIST) {
      g32([=](int k){ return ld4(Ap + k); },
          [=](int k){ return ld4(Wp + k); }, 1024, At, Wt, a00,a01,a10,a11);
    } else {
      const int tok = P.tgt[lr*SEQ + P.t];
      const float* Ep = P.emb + (size_t)tok*EMBD;
      g32([=](int k){ return (k < EMBD) ? ld4(Ep + k) : ld4(Ap + k - EMBD); },
          [=](int k){ return ld4(Wp + k); }, EMBD + HID, At, Wt, a00,a01,a10,a11);
    }
  } else {
    const float* Wp = P.W + (size_t)wrow*HID;
    const float* Ap = P.A + lr*HID;
    g32([=](int k){ return ld4(Ap + k); },
        [=](int k){ return ld4(Wp + k); }, 1024, At, Wt, a00,a01,a10,a11);
  }
  const int tn = tid & 15, tm = tid >> 4;
  res[(tm*2  )*33 + tn*2  ] = a00;
  res[(tm*2  )*33 + tn*2+1] = a01;
  res[(tm*2+1)*33 + tn*2  ] = a10;
  res[(tm*2+1)*33 + tn*2+1] = a11;
  __syncthreads();
  const int b = tid >> 3, j = tid & 7;
  const int n = nt*8 + j;
  float g4v[4];
  #pragma unroll
  for (int g = 0; g < 4; ++g) {
    const int gcol = g*1024 + n;
    float s = res[b*33 + g*8 + j] + P.bsum[gcol] + P.PgH[(size_t)b*G4 + gcol];
    if (LAYER == 0 && HOIST) s += P.gembt[(size_t)b*G4 + gcol];
    g4v[g] = s;
  }
  const float si = 1.f/(1.f+expf(-g4v[0]));
  const float sf = 1.f/(1.f+expf(-g4v[1]));
  const float so = 1.f/(1.f+expf(-g4v[3]));
  const int i = b*HID + n;
  const float cn = sf*P.c[i] + si*tanhf(g4v[2]);
  P.c[i] = cn;
  P.h[i] = so*tanhf(cn);
}

// ========== L3: proj (Pq = h1·[Wa1;Wc1]^T, direct) ∥ Whh0·h0 -> PgH0 ==========
struct PW {
  const float* h0; const float* h1;
  const float* Wa; const float* Wc; const float* Whh0;
  float* Pq; float* PgH0;
};

__global__ __launch_bounds__(256) void projwhh_k(PW P) {
  __shared__ float At[32*34], Wt[32*34];
  const int bid = blockIdx.x;
  const int tid = threadIdx.x;
  const int lr = tid >> 3;
  const float* Ap; const float* Wp; float* C; int ldc; int ncol;
  if (bid < 64) {           // proj rows [bid*32, +32) of [Wa1; Wc1]
    const int row = bid*32 + lr;
    Ap = P.h1 + lr*HID;
    Wp = (row < HID) ? (P.Wa + (size_t)row*(2*HID))
                     : (P.Wc + (size_t)(row - HID)*(2*HID));
    C = P.Pq; ldc = 2048; ncol = bid*32;
  } else {                  // Whh0·h0 -> PgH0, rows [(bid-64)*32, +32)
    const int nt = bid - 64;
    Ap = P.h0 + lr*HID;
    Wp = P.Whh0 + (size_t)(nt*32 + lr)*HID;
    C = P.PgH0; ldc = G4; ncol = nt*32;
  }
  float a00=0.f, a01=0.f, a10=0.f, a11=0.f;
  g32([=](int k){ return ld4(Ap + k); },
      [=](int k){ return ld4(Wp + k); }, 1024, At, Wt, a00,a01,a10,a11);
  const int tn = tid & 15, tm = tid >> 4;
  const int na = ncol + tn*2, ma = tm*2;
  C[(size_t)ma*ldc + na  ] = a00; C[(size_t)ma*ldc + na+1] = a01;
  C[(size_t)(ma+1)*ldc + na] = a10; C[(size_t)(ma+1)*ldc + na+1] = a11;
}

// ========== L4: attention (64 blocks) ∥ Whh1·h1 -> PgH1 (128 blocks) ==========
struct AW {
  const float* Pq; const float* PreAC; const float* va; const float* bc;
  const float* h1; const float* Whh1;
  float* AHt; float* PgH1;
};

__global__ __launch_bounds__(256) void attnwhh_k(AW P) {
  __shared__ float S[2176];
  const int bid = blockIdx.x;
  const int tid = threadIdx.x;
  if (bid < 64) {
    const int b = bid & 31, half = bid >> 5;
    float* QS  = S;            // [1024]
    float* sw  = S + 1024;     // [64]
    float* W64 = S + 1088;     // [64]
    for (int idx = tid; idx < HID; idx += 256) QS[idx] = P.Pq[(size_t)b*2048 + idx];
    __syncthreads();
    const int lane = tid & 63, wid = tid >> 6;
    float vreg[16];
    #pragma unroll
    for (int i2 = 0; i2 < 16; ++i2) vreg[i2] = P.va[lane + 64*i2];
    #pragma unroll
    for (int j = 0; j < 16; ++j) {
      const int te = wid*16 + j;
      const float* pr = P.PreAC + ((size_t)te*BATCH + b)*2048;
      float s = 0.f;
      #pragma unroll
      for (int i2 = 0; i2 < 16; ++i2) {
        const int idx = lane + 64*i2;
        s += vreg[i2] * tanhf(QS[idx] + pr[idx]);
      }
      #pragma unroll
      for (int off = 32; off; off >>= 1) s += __shfl_xor(s, off);
      if (lane == 0) sw[te] = s;
    }
    __syncthreads();
    if (tid < TENC) {
      const float v = sw[tid];
      float mx = v;
      #pragma unroll
      for (int off = 32; off; off >>= 1) mx = fmaxf(mx, __shfl_xor(mx, off));
      const float e = expf(v - mx);
      float sum = e;
      #pragma unroll
      for (int off = 32; off; off >>= 1) sum += __shfl_xor(sum, off);
      W64[tid] = e / sum;
    }
    __syncthreads();
    #pragma unroll
    for (int q = 0; q < 2; ++q) {
      const int hh = half*512 + q*256 + tid;
      float acc = 0.f;
      #pragma unroll 8
      for (int te = 0; te < TENC; ++te)
        acc += W64[te] * P.PreAC[((size_t)te*BATCH + b)*2048 + HID + hh];
      const float hc = P.Pq[(size_t)b*2048 + HID + hh] + P.bc[hh];
      P.AHt[(size_t)b*HID + hh] = tanhf(acc + hc);
    }
  } else {
    float* At = S; float* Wt = S + 1088;
    const int nt = bid - 64;
    const int lr = tid >> 3;
    const float* Ap = P.h1 + lr*HID;
    const float* Wp = P.Whh1 + (size_t)(nt*32 + lr)*HID;
    float a00=0.f, a01=0.f, a10=0.f, a11=0.f;
    g32([=](int k){ return ld4(Ap + k); },
        [=](int k){ return ld4(Wp + k); }, 1024, At, Wt, a00,a01,a10,a11);
    const int tn = tid & 15, tm = tid >> 4;
    const int na = nt*32 + tn*2, ma = tm*2;
    P.PgH1[(size_t)ma*G4 + na  ] = a00; P.PgH1[(size_t)ma*G4 + na+1] = a01;
    P.PgH1[(size_t)(ma+1)*G4 + na] = a10; P.PgH1[(size_t)(ma+1)*G4 + na+1] = a11;
  }
}

// ========== prologue: PgH0 = Whh0·h0_init, PgH1 = Whh1·h1_init ==========
struct WI {
  const float* h0; const float* h1; const float* Whh0; const float* Whh1;
  float* PgH0; float* PgH1;
};

__global__ __launch_bounds__(256) void whhinit_k(WI P) {
  __shared__ float At[32*34], Wt[32*34];
  const int bid = blockIdx.x;
  const int tid = threadIdx.x;
  const int lr = tid >> 3;
  const float* Ap; const float* Wp; float* C; int nt;
  if (bid < 128) { nt = bid;       Ap = P.h0 + lr*HID; Wp = P.Whh0 + (size_t)(nt*32+lr)*HID; C = P.PgH0; }
  else           { nt = bid - 128; Ap = P.h1 + lr*HID; Wp = P.Whh1 + (size_t)(nt*32+lr)*HID; C = P.PgH1; }
  float a00=0.f, a01=0.f, a10=0.f, a11=0.f;
  g32([=](int k){ return ld4(Ap + k); },
      [=](int k){ return ld4(Wp + k); }, 1024, At, Wt, a00,a01,a10,a11);
  const int tn = tid & 15, tm = tid >> 4;
  const int na = nt*32 + tn*2, ma = tm*2;
  C[(size_t)ma*G4 + na  ] = a00; C[(size_t)ma*G4 + na+1] = a01;
  C[(size_t)(ma+1)*G4 + na] = a10; C[(size_t)(ma+1)*G4 + na+1] = a11;
}

// ========== fp32 wide GEMM (fallback logits / PreAC / Gemb) ==========
struct WGP {
  const float* A; const float* W; const float* W2; const float* bias;
  const int* tgt; const float* emb;
  float* C; int ldc;
};

template<int WM>
__device__ __forceinline__ float4 ldWL(const WGP& P, int r, int k) {
  if (WM == 0) return ld4(P.W + (size_t)r * 1024 + k);
  if (WM == 2) return ld4(P.W + (size_t)r * (EMBD + HID) + k);
  if (r < HID) return ld4(P.W  + (size_t)r * (2*HID) + HID + k);
  return ld4(P.W2 + (size_t)(r - HID) * (2*HID) + HID + k);
}

template<int WM>
__device__ __forceinline__ float4 ldAL(const WGP& P, int row, int k) {
  if (WM == 2) {
    const int tok = P.tgt[(row & 31) * SEQ + (row >> 5)];
    return ld4(P.emb + (size_t)tok * EMBD + k);
  }
  return ld4(P.A + (size_t)row * 1024 + k);
}

template<int WM>
__global__ __launch_bounds__(256, 2) void gemmL(WGP P) {
  constexpr int KK = (WM == 2) ? 512 : 1024;
  __shared__ float At[32*36];
  __shared__ float Wt[32*260];
  const int tid = threadIdx.x;
  const int m0 = blockIdx.x * 32;
  const int n0 = blockIdx.y * 256;
  const int lr = tid >> 3, lc = (tid & 7) << 2;
  const int tn = tid & 31, tm = tid >> 5;
  float acc[4][8];
  #pragma unroll
  for (int i = 0; i < 4; ++i)
    #pragma unroll
    for (int x = 0; x < 8; ++x) acc[i][x] = 0.f;

  float4 av = ldAL<WM>(P, m0 + lr, lc);
  float4 wv[8];
  #pragma unroll
  for (int it = 0; it < 8; ++it) wv[it] = ldWL<WM>(P, n0 + lr + it*32, lc);

  for (int k0 = 0; k0 < KK; k0 += 32) {
    float4 avn, wvn[8];
    if (k0 + 32 < KK) {
      avn = ldAL<WM>(P, m0 + lr, k0 + 32 + lc);
      #pragma unroll
      for (int it = 0; it < 8; ++it) wvn[it] = ldWL<WM>(P, n0 + lr + it*32, k0 + 32 + lc);
    }
    __syncthreads();
    At[(lc+0)*36+lr]=av.x; At[(lc+1)*36+lr]=av.y; At[(lc+2)*36+lr]=av.z; At[(lc+3)*36+lr]=av.w;
    #pragma unroll
    for (int it = 0; it < 8; ++it) {
      const int r = lr + it*32;
      Wt[(lc+0)*260+r]=wv[it].x; Wt[(lc+1)*260+r]=wv[it].y;
      Wt[(lc+2)*260+r]=wv[it].z; Wt[(lc+3)*260+r]=wv[it].w;
    }
    __syncthreads();
    #pragma unroll
    for (int kk = 0; kk < 32; ++kk) {
      const float4 a  = *reinterpret_cast<const float4*>(&At[kk*36 + tm*4]);
      const float4 w0 = *reinterpret_cast<const float4*>(&Wt[kk*260 + tn*8]);
      const float4 w1 = *reinterpret_cast<const float4*>(&Wt[kk*260 + tn*8 + 4]);
      #pragma unroll
      for (int i = 0; i < 4; ++i) {
        const float ai = (&a.x)[i];
        acc[i][0]+=ai*w0.x; acc[i][1]+=ai*w0.y; acc[i][2]+=ai*w0.z; acc[i][3]+=ai*w0.w;
        acc[i][4]+=ai*w1.x; acc[i][5]+=ai*w1.y; acc[i][6]+=ai*w1.z; acc[i][7]+=ai*w1.w;
      }
    }
    av = avn;
    #pragma unroll
    for (int it = 0; it < 8; ++it) wv[it] = wvn[it];
  }
  const int na = n0 + tn*8, ma = m0 + tm*4;
  float bb[8];
  #pragma unroll
  for (int x = 0; x < 8; ++x) {
    if (WM == 0)      bb[x] = P.bias[na+x];
    else if (WM == 1) bb[x] = (na + x < HID) ? P.bias[na+x] : 0.f;
    else              bb[x] = 0.f;
  }
  #pragma unroll
  for (int i = 0; i < 4; ++i)
    #pragma unroll
    for (int x = 0; x < 8; ++x)
      P.C[(size_t)(ma+i)*P.ldc + na + x] = acc[i][x] + bb[x];
}

// ========== fp32 -> bf16 hi/lo split ==========
__global__ __launch_bounds__(256) void cvt_k(const float* __restrict__ src,
                                             unsigned short* __restrict__ hi,
                                             unsigned short* __restrict__ lo, int n) {
  int i = (blockIdx.x*256 + threadIdx.x) * 4;
  const int stride = gridDim.x * 256 * 4;
  for (; i < n; i += stride) {
    const float4 v = ld4(src + i);
    us4 h, l;
    h.x = f2bf(v.x); l.x = f2bf(v.x - bf2f(h.x));
    h.y = f2bf(v.y); l.y = f2bf(v.y - bf2f(h.y));
    h.z = f2bf(v.z); l.z = f2bf(v.z - bf2f(h.z));
    h.w = f2bf(v.w); l.w = f2bf(v.w - bf2f(h.w));
    *reinterpret_cast<us4*>(hi + i) = h;
    *reinterpret_cast<us4*>(lo + i) = l;
  }
}

// ========== split-bf16 MFMA logits: out = AH·Wo^T + bo ==========
// block tile 64m x 128n, 4 waves (w&1 -> m-half, w>>1 -> n-half), K-chunks of 32.
struct LM {
  const unsigned short* Ahi; const unsigned short* Alo;
  const unsigned short* Bhi; const unsigned short* Blo;
  const float* bo; float* out;
};

__global__ __launch_bounds__(256) void logits_mfma(LM P) {
  __shared__ unsigned short sA[2][4][64][8];    // [hi/lo][kgroup][row][8]
  __shared__ unsigned short sB[2][4][128][8];
  const int tid = threadIdx.x;
  const int m0 = blockIdx.x * 64;
  const int n0 = blockIdx.y * 128;
  const int w = tid >> 6, l = tid & 63;
  const int mb = (w & 1) * 32, nb = (w >> 1) * 64;
  f32x4 acc[2][4];
  #pragma unroll
  for (int mt = 0; mt < 2; ++mt)
    #pragma unroll
    for (int nt = 0; nt < 4; ++nt) acc[mt][nt] = 0.f;

  const int arow = tid >> 2, akg = tid & 3;          // AH stage: 64 rows x 4 kg
  const int brow = tid >> 1, bkg = (tid & 1) * 2;    // Wo stage: 128 rows x {kg, kg+1}
  short8 pah, pal, pbh0, pbh1, pbl0, pbl1;
  {
    const size_t ao = (size_t)(m0 + arow)*HID + akg*8;
    const size_t bo0 = (size_t)(n0 + brow)*HID + bkg*8;
    pah  = *reinterpret_cast<const short8*>(P.Ahi + ao);
    pal  = *reinterpret_cast<const short8*>(P.Alo + ao);
    pbh0 = *reinterpret_cast<const short8*>(P.Bhi + bo0);
    pbh1 = *reinterpret_cast<const short8*>(P.Bhi + bo0 + 8);
    pbl0 = *reinterpret_cast<const short8*>(P.Blo + bo0);
    pbl1 = *reinterpret_cast<const short8*>(P.Blo + bo0 + 8);
  }
  for (int kc = 0; kc < 32; ++kc) {
    __syncthreads();
    *reinterpret_cast<short8*>(&sA[0][akg][arow][0]) = pah;
    *reinterpret_cast<short8*>(&sA[1][akg][arow][0]) = pal;
    *reinterpret_cast<short8*>(&sB[0][bkg  ][brow][0]) = pbh0;
    *reinterpret_cast<short8*>(&sB[0][bkg+1][brow][0]) = pbh1;
    *reinterpret_cast<short8*>(&sB[1][bkg  ][brow][0]) = pbl0;
    *reinterpret_cast<short8*>(&sB[1][bkg+1][brow][0]) = pbl1;
    __syncthreads();
    if (kc + 1 < 32) {
      const size_t ao = (size_t)(m0 + arow)*HID + (kc+1)*32 + akg*8;
      const size_t bo0 = (size_t)(n0 + brow)*HID + (kc+1)*32 + bkg*8;
      pah  = *reinterpret_cast<const short8*>(P.Ahi + ao);
      pal  = *reinterpret_cast<const short8*>(P.Alo + ao);
      pbh0 = *reinterpret_cast<const short8*>(P.Bhi + bo0);
      pbh1 = *reinterpret_cast<const short8*>(P.Bhi + bo0 + 8);
      pbl0 = *reinterpret_cast<const short8*>(P.Blo + bo0);
      pbl1 = *reinterpret_cast<const short8*>(P.Blo + bo0 + 8);
    }
    const int kg = l >> 4, rr = l & 15;
    short8 ah[2], al[2];
    #pragma unroll
    for (int mt = 0; mt < 2; ++mt) {
      ah[mt] = *reinterpret_cast<const short8*>(&sA[0][kg][mb + mt*16 + rr][0]);
      al[mt] = *reinterpret_cast<const short8*>(&sA[1][kg][mb + mt*16 + rr][0]);
    }
    #pragma unroll
    for (int nt = 0; nt < 4; ++nt) {
      const short8 bh = *reinterpret_cast<const short8*>(&sB[0][kg][nb + nt*16 + rr][0]);
      const short8 bl = *reinterpret_cast<const short8*>(&sB[1][kg][nb + nt*16 + rr][0]);
      #pragma unroll
      for (int mt = 0; mt < 2; ++mt) {
        acc[mt][nt] = __builtin_amdgcn_mfma_f32_16x16x32_bf16(ah[mt], bh, acc[mt][nt], 0, 0, 0);
        acc[mt][nt] = __builtin_amdgcn_mfma_f32_16x16x32_bf16(ah[mt], bl, acc[mt][nt], 0, 0, 0);
        acc[mt][nt] = __builtin_amdgcn_mfma_f32_16x16x32_bf16(al[mt], bh, acc[mt][nt], 0, 0, 0);
      }
    }
  }
  #pragma unroll
  for (int mt = 0; mt < 2; ++mt) {
    #pragma unroll
    for (int nt = 0; nt < 4; ++nt) {
      #pragma unroll
      for (int r = 0; r < 4; ++r) {
        const int row = m0 + mb + mt*16 + (l >> 4)*4 + r;
        const int col = n0 + nb + nt*16 + (l & 15);
        if (row < NSTEP*BATCH)
          P.out[(size_t)row*VOCAB + col] = acc[mt][nt][r] + P.bo[col];
      }
    }
  }
}

// ========== per-(b,t) log-softmax + argmax ==========
__global__ __launch_bounds__(256) void lsm_k(float* __restrict__ out,
                                             float* __restrict__ words) {
  const int b = blockIdx.x;
  const int t = blockIdx.y;
  float* row = out + ((size_t)t*BATCH + b)*VOCAB;
  const int tid = threadIdx.x;
  float m = -INFINITY; int mi = 0;
  for (int v = tid; v < VOCAB; v += 256) {
    const float x = row[v];
    if (x > m) { m = x; mi = v; }
  }
  __shared__ float sm[256]; __shared__ int si[256];
  sm[tid] = m; si[tid] = mi;
  __syncthreads();
  for (int s2 = 128; s2; s2 >>= 1) {
    if (tid < s2) {
      const float om = sm[tid+s2]; const int oi = si[tid+s2];
      if (om > sm[tid] || (om == sm[tid] && oi < si[tid])) { sm[tid]=om; si[tid]=oi; }
    }
    __syncthreads();
  }
  const float mx = sm[0]; const int amax = si[0];
  float s = 0.f;
  for (int v = tid; v < VOCAB; v += 256) s += expf(row[v]-mx);
  __shared__ float ss[256];
  ss[tid] = s; __syncthreads();
  for (int s2=128; s2; s2>>=1) { if (tid < s2) ss[tid] += ss[tid+s2]; __syncthreads(); }
  const float lse = logf(ss[0]) + mx;
  for (int v = tid; v < VOCAB; v += 256) row[v] = row[v] - lse;
  if (tid == 0) words[(size_t)t*BATCH + b] = (float)amax;
}

__global__ __launch_bounds__(256) void init_k(const float* __restrict__ enc_h,
                                              const float* __restrict__ enc_c,
                                              const float* __restrict__ bih0,
                                              const float* __restrict__ bhh0,
                                              const float* __restrict__ bih1,
                                              const float* __restrict__ bhh1,
                                              float* h0, float* h1, float* c0,
                                              float* c1, float* zbuf,
                                              float* bsum0, float* bsum1) {
  const int i = blockIdx.x*256 + threadIdx.x;
  if (i < BATCH*HID) {
    h0[i] = enc_h[i]; h1[i] = enc_h[BATCH*HID + i];
    c0[i] = enc_c[i]; c1[i] = enc_c[BATCH*HID + i];
    zbuf[i] = 0.f;
  }
  if (i < G4) {
    bsum0[i] = bih0[i] + bhh0[i];
    bsum1[i] = bih1[i] + bhh1[i];
  }
}

extern "C" void kernel_launch(void* const* d_in, const int* in_sizes, int n_in,
                              void* d_out, int out_size, void* d_ws, size_t ws_size,
                              hipStream_t stream) {
  const int*   tgt   = (const int*)d_in[0];
  const float* enc_h = (const float*)d_in[1];
  const float* enc_c = (const float*)d_in[2];
  const float* enc   = (const float*)d_in[3];
  const float* emb   = (const float*)d_in[4];
  const float* Wih0  = (const float*)d_in[5];
  const float* Whh0  = (const float*)d_in[6];
  const float* bih0  = (const float*)d_in[7];
  const float* bhh0  = (const float*)d_in[8];
  const float* Wih1  = (const float*)d_in[9];
  const float* Whh1  = (const float*)d_in[10];
  const float* bih1  = (const float*)d_in[11];
  const float* bhh1  = (const float*)d_in[12];
  const float* Wa    = (const float*)d_in[13];
  const float* ba    = (const float*)d_in[14];
  const float* va    = (const float*)d_in[15];
  const float* Wc    = (const float*)d_in[16];
  const float* bc    = (const float*)d_in[17];
  const float* Wo    = (const float*)d_in[18];
  const float* bo    = (const float*)d_in[19];

  float* ws = (float*)d_ws;
  size_t off = 0;
  auto alloc = [&](size_t n) { float* p = ws + off; off += n; return p; };
  float* PreAC = alloc((size_t)2048*2048);
  float* AH    = alloc((size_t)2048*1024);          // rows 0..2015 used
  float* Pq    = alloc((size_t)BATCH*2048);
  float* PgH0  = alloc((size_t)BATCH*G4);
  float* PgH1  = alloc((size_t)BATCH*G4);
  float* h0    = alloc(BATCH*HID);
  float* h1v   = alloc(BATCH*HID);
  float* c0    = alloc(BATCH*HID);
  float* c1v   = alloc(BATCH*HID);
  float* zbuf  = alloc(BATCH*HID);
  float* bsum0 = alloc(G4);
  float* bsum1 = alloc(G4);

  float* Gemb = ws + off;
  const size_t off_gemb = off + (size_t)NSTEP*BATCH*G4;
  const bool hoist = ws_size >= off_gemb * sizeof(float);
  size_t off2 = hoist ? off_gemb : off;

  unsigned short* bfbase = (unsigned short*)(ws + off2);
  const size_t nAH = (size_t)2048*1024, nWo = (size_t)VOCAB*1024;
  unsigned short* AHhi = bfbase;
  unsigned short* AHlo = AHhi + nAH;
  unsigned short* Wohi = AHlo + nAH;
  unsigned short* Wolo = Wohi + nWo;
  const bool mfma_ok = ws_size >= off2*sizeof(float) + (2*nAH + 2*nWo)*sizeof(unsigned short);

  float* out   = (float*)d_out;
  float* words = out + (size_t)NSTEP*BATCH*VOCAB;

  init_k<<<dim3(128), 256, 0, stream>>>(enc_h, enc_c, bih0, bhh0, bih1, bhh1,
                                        h0, h1v, c0, c1v, zbuf, bsum0, bsum1);

  { // PreAC = enc @ [Wa2; Wc2]^T + [ba; 0]
    WGP p = {}; p.A = enc; p.W = Wa; p.W2 = Wc; p.bias = ba; p.C = PreAC; p.ldc = 2048;
    gemmL<1><<<dim3(64, 8), 256, 0, stream>>>(p);
  }
  if (hoist) { // Gemb = emb[tok] @ Wih0[:, :512]^T for all (t,b)
    WGP p = {}; p.W = Wih0; p.tgt = tgt; p.emb = emb; p.C = Gemb; p.ldc = G4;
    gemmL<2><<<dim3(NSTEP*BATCH/32, G4/256), 256, 0, stream>>>(p);
  }
  if (mfma_ok) { // Wo -> bf16 hi/lo (once)
    cvt_k<<<dim3(4096), 256, 0, stream>>>(Wo, Wohi, Wolo, VOCAB*1024);
  }
  { // PgH0/PgH1 from initial h
    WI p; p.h0 = h0; p.h1 = h1v; p.Whh0 = Whh0; p.Whh1 = Whh1;
    p.PgH0 = PgH0; p.PgH1 = PgH1;
    whhinit_k<<<dim3(256), 256, 0, stream>>>(p);
  }

  for (int t = 0; t < NSTEP; ++t) {
    const float* ah_prev = t ? (AH + (size_t)(t-1)*BATCH*HID) : zbuf;
    { // L1: gates0 + cell0 (block-local)
      GC p = {}; p.tgt = tgt; p.emb = emb; p.t = t;
      p.A = ah_prev; p.W = Wih0;
      p.gembt = Gemb + (size_t)t*BATCH*G4;
      p.PgH = PgH0; p.bsum = bsum0; p.h = h0; p.c = c0;
      if (hoist) gcell_k<0,1><<<dim3(128), 256, 0, stream>>>(p);
      else       gcell_k<0,0><<<dim3(128), 256, 0, stream>>>(p);
    }
    { // L2: gates1 + cell1
      GC p = {}; p.A = h0; p.W = Wih1;
      p.PgH = PgH1; p.bsum = bsum1; p.h = h1v; p.c = c1v; p.t = t;
      gcell_k<1,0><<<dim3(128), 256, 0, stream>>>(p);
    }
    { // L3: proj (direct Pq) ∥ Whh0·h0_t -> PgH0 (for t+1)
      PW p; p.h0 = h0; p.h1 = h1v; p.Wa = Wa; p.Wc = Wc; p.Whh0 = Whh0;
      p.Pq = Pq; p.PgH0 = PgH0;
      projwhh_k<<<dim3(192), 256, 0, stream>>>(p);
    }
    { // L4: attention -> AH[t] ∥ Whh1·h1_t -> PgH1 (for t+1)
      AW p; p.Pq = Pq; p.PreAC = PreAC; p.va = va; p.bc = bc;
      p.h1 = h1v; p.Whh1 = Whh1;
      p.AHt = AH + (size_t)t*BATCH*HID; p.PgH1 = PgH1;
      attnwhh_k<<<dim3(192), 256, 0, stream>>>(p);
    }
  }

  if (mfma_ok) {
    cvt_k<<<dim3(2048), 256, 0, stream>>>(AH, AHhi, AHlo, NSTEP*BATCH*HID);
    LM p; p.Ahi = AHhi; p.Alo = AHlo; p.Bhi = Wohi; p.Blo = Wolo;
    p.bo = bo; p.out = out;
    logits_mfma<<<dim3(32, VOCAB/128), 256, 0, stream>>>(p);
  } else {
    WGP p = {}; p.A = AH; p.W = Wo; p.bias = bo; p.C = out; p.ldc = VOCAB;
    gemmL<0><<<dim3(NSTEP*BATCH/32, VOCAB/256), 256, 0, stream>>>(p);
  }
  lsm_k<<<dim3(BATCH, NSTEP), 256, 0, stream>>>(out, words);
}

// Round 10
// 7071.767 us; speedup vs baseline: 3.0342x; 1.8412x over previous
//
#include <hip/hip_runtime.h>
#include <math.h>

#define VOCAB 32000
#define EMBD  512
#define HID   1024
#define BATCH 32
#define SEQ   64
#define TENC  64
#define NSTEP 63
#define G4    4096

typedef __attribute__((ext_vector_type(8))) short short8;
typedef __attribute__((ext_vector_type(4))) float f32x4;
typedef __attribute__((ext_vector_type(4))) unsigned short us4;

__device__ __forceinline__ float4 ld4(const float* p) {
  return *reinterpret_cast<const float4*>(p);
}
__device__ __forceinline__ unsigned short f2bf(float x) {
  unsigned u = __float_as_uint(x);
  return (unsigned short)((u + 0x7fffu + ((u >> 16) & 1u)) >> 16);
}
__device__ __forceinline__ float bf2f(unsigned short h) {
  return __uint_as_float(((unsigned)h) << 16);
}

// ===== 4-team 32x32 GEMM core (1024-thr block). Team computes its K-chunk;
// partial [32b][32r] goes to res[team]. Caller syncs then reduces. =====
template<class FA, class FW>
__device__ __forceinline__ void g32x4(int team, int ttid, FA fa, FW fw, int KT,
                                      float* tiles, float* res) {
  float* At = tiles + team * 2176;
  float* Wt = At + 1088;
  const int lr = ttid >> 3, lc = (ttid & 7) << 2;
  const int tn = ttid & 15, tm = ttid >> 4;
  float a00=0.f, a01=0.f, a10=0.f, a11=0.f;
  float4 av = fa(lc);
  float4 wv = fw(lc);
  for (int k0 = 0; k0 < KT; k0 += 32) {
    float4 avn, wvn;
    if (k0 + 32 < KT) { avn = fa(k0 + 32 + lc); wvn = fw(k0 + 32 + lc); }
    __syncthreads();
    At[(lc+0)*34+lr]=av.x; At[(lc+1)*34+lr]=av.y; At[(lc+2)*34+lr]=av.z; At[(lc+3)*34+lr]=av.w;
    Wt[(lc+0)*34+lr]=wv.x; Wt[(lc+1)*34+lr]=wv.y; Wt[(lc+2)*34+lr]=wv.z; Wt[(lc+3)*34+lr]=wv.w;
    __syncthreads();
    #pragma unroll
    for (int kk = 0; kk < 32; ++kk) {
      const float2 a = *reinterpret_cast<const float2*>(&At[kk*34 + tm*2]);
      const float2 w = *reinterpret_cast<const float2*>(&Wt[kk*34 + tn*2]);
      a00 += a.x*w.x; a01 += a.x*w.y; a10 += a.y*w.x; a11 += a.y*w.y;
    }
    av = avn; wv = wvn;
  }
  float* r = res + team * 1056;
  r[(tm*2  )*33 + tn*2  ] = a00;
  r[(tm*2  )*33 + tn*2+1] = a01;
  r[(tm*2+1)*33 + tn*2  ] = a10;
  r[(tm*2+1)*33 + tn*2+1] = a11;
}

// whh-style block: C[b][nt*32+cc] = (W·h^T)^T fully reduced, C row stride ldc
__device__ __forceinline__ void whh_block(const float* h, const float* W, float* C,
                                          int nt, int ldc, float* tiles, float* res) {
  const int tid = threadIdx.x, team = tid >> 8, ttid = tid & 255;
  const int lr = ttid >> 3;
  const int kb = team * 256;
  const float* Ap = h + lr*HID + kb;
  const float* Wp = W + (size_t)(nt*32 + lr)*HID + kb;
  g32x4(team, ttid, [=](int k){ return ld4(Ap + k); },
        [=](int k){ return ld4(Wp + k); }, 256, tiles, res);
  __syncthreads();
  const int b = tid >> 5, cc = tid & 31;
  const float v = res[b*33+cc] + res[1056 + b*33+cc]
                + res[2112 + b*33+cc] + res[3168 + b*33+cc];
  C[(size_t)b*ldc + nt*32 + cc] = v;
}

// ===== L1: gates0 + cell0 (block nt owns 8 n-cols x 4 gates, 32 b) =====
struct GC {
  const int* tgt; const float* emb;
  const float* A;        // ah_prev
  const float* W;        // Wih0
  const float* gembt; const float* PgH; const float* bsum;
  float* h; float* c; int t;
};

template<int LAYER, int HOIST>
__device__ __forceinline__ void gcell_block(const GC& P, int nt, float* tiles, float* res) {
  const int tid = threadIdx.x, team = tid >> 8, ttid = tid & 255;
  const int lr = ttid >> 3;
  const int wrow = (lr >> 3)*1024 + nt*8 + (lr & 7);
  if (LAYER == 0) {
    if (HOIST) {
      const int kb = team * 256;
      const float* Ap = P.A + lr*HID + kb;
      const float* Wp = P.W + (size_t)wrow*(EMBD+HID) + EMBD + kb;
      g32x4(team, ttid, [=](int k){ return ld4(Ap + k); },
            [=](int k){ return ld4(Wp + k); }, 256, tiles, res);
    } else {
      const int kb = team * 384;
      const float* Wp = P.W + (size_t)wrow*(EMBD+HID) + kb;
      const int tok = P.tgt[lr*SEQ + P.t];
      const float* Ep = P.emb + (size_t)tok*EMBD;
      const float* Ap = P.A + lr*HID;
      g32x4(team, ttid,
            [=](int k){ const int kg = kb + k;
                        return (kg < EMBD) ? ld4(Ep + kg) : ld4(Ap + kg - EMBD); },
            [=](int k){ return ld4(Wp + k); }, 384, tiles, res);
    }
  } else {
    const int kb = team * 256;
    const float* Ap = P.A + lr*HID + kb;
    const float* Wp = P.W + (size_t)wrow*HID + kb;
    g32x4(team, ttid, [=](int k){ return ld4(Ap + k); },
          [=](int k){ return ld4(Wp + k); }, 256, tiles, res);
  }
  __syncthreads();
  if (tid < 256) {
    const int b = tid >> 3, j = tid & 7;
    const int n = nt*8 + j;
    float g4v[4];
    #pragma unroll
    for (int g = 0; g < 4; ++g) {
      const int gcol = g*1024 + n;
      const int r = g*8 + j;
      float s = P.bsum[gcol] + P.PgH[(size_t)b*G4 + gcol]
              + res[b*33+r] + res[1056 + b*33+r] + res[2112 + b*33+r] + res[3168 + b*33+r];
      if (LAYER == 0 && HOIST) s += P.gembt[(size_t)b*G4 + gcol];
      g4v[g] = s;
    }
    const float si = 1.f/(1.f+expf(-g4v[0]));
    const float sf = 1.f/(1.f+expf(-g4v[1]));
    const float so = 1.f/(1.f+expf(-g4v[3]));
    const int i = b*HID + n;
    const float cn = sf*P.c[i] + si*tanhf(g4v[2]);
    P.c[i] = cn;
    P.h[i] = so*tanhf(cn);
  }
}

template<int HOIST>
__global__ __launch_bounds__(1024) void l1_k(GC P) {
  __shared__ float tiles[4*2176];
  __shared__ float res[4*1056];
  gcell_block<0,HOIST>(P, blockIdx.x, tiles, res);
}

// ===== L2: gates1+cell1 (128 blocks) ∥ Whh0·h0_t -> PgH0 (128 blocks) =====
struct L2P { GC gc; const float* h0; const float* Whh0; float* PgH0; };

__global__ __launch_bounds__(1024) void l2_k(L2P P) {
  __shared__ float tiles[4*2176];
  __shared__ float res[4*1056];
  const int bid = blockIdx.x;
  if (bid < 128) gcell_block<1,0>(P.gc, bid, tiles, res);
  else           whh_block(P.h0, P.Whh0, P.PgH0, bid - 128, G4, tiles, res);
}

// ===== L3: Pq = h1·[Wa1;Wc1]^T (64 blocks, full reduce) =====
struct L3P { const float* h1; const float* Wa; const float* Wc; float* Pq; };

__global__ __launch_bounds__(1024) void l3_k(L3P P) {
  __shared__ float tiles[4*2176];
  __shared__ float res[4*1056];
  const int nt = blockIdx.x;               // 0..63
  const int tid = threadIdx.x, team = tid >> 8, ttid = tid & 255;
  const int lr = ttid >> 3;
  const int kb = team * 256;
  const int row = nt*32 + lr;
  const float* Ap = P.h1 + lr*HID + kb;
  const float* Wp = ((row < HID) ? (P.Wa + (size_t)row*(2*HID))
                                 : (P.Wc + (size_t)(row - HID)*(2*HID))) + kb;
  g32x4(team, ttid, [=](int k){ return ld4(Ap + k); },
        [=](int k){ return ld4(Wp + k); }, 256, tiles, res);
  __syncthreads();
  const int b = tid >> 5, cc = tid & 31;
  const float v = res[b*33+cc] + res[1056 + b*33+cc]
                + res[2112 + b*33+cc] + res[3168 + b*33+cc];
  P.Pq[(size_t)b*2048 + nt*32 + cc] = v;
}

// ===== L4: attention (32 blocks) ∥ Whh1·h1_t -> PgH1 (128 blocks) =====
struct L4P {
  const float* Pq; const float* PreAC; const float* va; const float* bc;
  const float* h1; const float* Whh1;
  float* AHt; float* PgH1;
};

__global__ __launch_bounds__(1024) void l4_k(L4P P) {
  __shared__ float tiles[4*2176];
  __shared__ float res[4*1056];
  const int bid = blockIdx.x;
  const int tid = threadIdx.x;
  if (bid < 32) {
    const int b = bid;
    float* QS  = tiles;            // [1024]
    float* sw  = tiles + 1024;     // [64]
    float* W64 = tiles + 1088;     // [64]
    QS[tid] = P.Pq[(size_t)b*2048 + tid];
    __syncthreads();
    const int lane = tid & 63, wid = tid >> 6;    // 16 waves
    float vreg[16];
    #pragma unroll
    for (int i2 = 0; i2 < 16; ++i2) vreg[i2] = P.va[lane + 64*i2];
    #pragma unroll
    for (int j = 0; j < 4; ++j) {
      const int te = wid*4 + j;
      const float* pr = P.PreAC + ((size_t)te*BATCH + b)*2048;
      float s = 0.f;
      #pragma unroll
      for (int i2 = 0; i2 < 16; ++i2) {
        const int idx = lane + 64*i2;
        s += vreg[i2] * tanhf(QS[idx] + pr[idx]);
      }
      #pragma unroll
      for (int off = 32; off; off >>= 1) s += __shfl_xor(s, off);
      if (lane == 0) sw[te] = s;
    }
    __syncthreads();
    if (tid < TENC) {
      const float v = sw[tid];
      float mx = v;
      #pragma unroll
      for (int off = 32; off; off >>= 1) mx = fmaxf(mx, __shfl_xor(mx, off));
      const float e = expf(v - mx);
      float sum = e;
      #pragma unroll
      for (int off = 32; off; off >>= 1) sum += __shfl_xor(sum, off);
      W64[tid] = e / sum;
    }
    __syncthreads();
    const int hh = tid;
    float acc = 0.f;
    #pragma unroll 8
    for (int te = 0; te < TENC; ++te)
      acc += W64[te] * P.PreAC[((size_t)te*BATCH + b)*2048 + HID + hh];
    const float hc = P.Pq[(size_t)b*2048 + HID + hh] + P.bc[hh];
    P.AHt[(size_t)b*HID + hh] = tanhf(acc + hc);
  } else {
    whh_block(P.h1, P.Whh1, P.PgH1, bid - 32, G4, tiles, res);
  }
}

// ===== prologue: PgH0/PgH1 from initial h (256 blocks) =====
struct WIP {
  const float* h0; const float* h1; const float* Whh0; const float* Whh1;
  float* PgH0; float* PgH1;
};

__global__ __launch_bounds__(1024) void whhinit_k(WIP P) {
  __shared__ float tiles[4*2176];
  __shared__ float res[4*1056];
  const int bid = blockIdx.x;
  if (bid < 128) whh_block(P.h0, P.Whh0, P.PgH0, bid, G4, tiles, res);
  else           whh_block(P.h1, P.Whh1, P.PgH1, bid - 128, G4, tiles, res);
}

// ===== fp32 wide GEMM (PreAC / Gemb / fallback logits) =====
struct WGP {
  const float* A; const float* W; const float* W2; const float* bias;
  const int* tgt; const float* emb;
  float* C; int ldc;
};

template<int WM>
__device__ __forceinline__ float4 ldWL(const WGP& P, int r, int k) {
  if (WM == 0) return ld4(P.W + (size_t)r * 1024 + k);
  if (WM == 2) return ld4(P.W + (size_t)r * (EMBD + HID) + k);
  if (r < HID) return ld4(P.W  + (size_t)r * (2*HID) + HID + k);
  return ld4(P.W2 + (size_t)(r - HID) * (2*HID) + HID + k);
}

template<int WM>
__device__ __forceinline__ float4 ldAL(const WGP& P, int row, int k) {
  if (WM == 2) {
    const int tok = P.tgt[(row & 31) * SEQ + (row >> 5)];
    return ld4(P.emb + (size_t)tok * EMBD + k);
  }
  return ld4(P.A + (size_t)row * 1024 + k);
}

template<int WM>
__global__ __launch_bounds__(256, 2) void gemmL(WGP P) {
  constexpr int KK = (WM == 2) ? 512 : 1024;
  __shared__ float At[32*36];
  __shared__ float Wt[32*260];
  const int tid = threadIdx.x;
  const int m0 = blockIdx.x * 32;
  const int n0 = blockIdx.y * 256;
  const int lr = tid >> 3, lc = (tid & 7) << 2;
  const int tn = tid & 31, tm = tid >> 5;
  float acc[4][8];
  #pragma unroll
  for (int i = 0; i < 4; ++i)
    #pragma unroll
    for (int x = 0; x < 8; ++x) acc[i][x] = 0.f;

  float4 av = ldAL<WM>(P, m0 + lr, lc);
  float4 wv[8];
  #pragma unroll
  for (int it = 0; it < 8; ++it) wv[it] = ldWL<WM>(P, n0 + lr + it*32, lc);

  for (int k0 = 0; k0 < KK; k0 += 32) {
    float4 avn, wvn[8];
    if (k0 + 32 < KK) {
      avn = ldAL<WM>(P, m0 + lr, k0 + 32 + lc);
      #pragma unroll
      for (int it = 0; it < 8; ++it) wvn[it] = ldWL<WM>(P, n0 + lr + it*32, k0 + 32 + lc);
    }
    __syncthreads();
    At[(lc+0)*36+lr]=av.x; At[(lc+1)*36+lr]=av.y; At[(lc+2)*36+lr]=av.z; At[(lc+3)*36+lr]=av.w;
    #pragma unroll
    for (int it = 0; it < 8; ++it) {
      const int r = lr + it*32;
      Wt[(lc+0)*260+r]=wv[it].x; Wt[(lc+1)*260+r]=wv[it].y;
      Wt[(lc+2)*260+r]=wv[it].z; Wt[(lc+3)*260+r]=wv[it].w;
    }
    __syncthreads();
    #pragma unroll
    for (int kk = 0; kk < 32; ++kk) {
      const float4 a  = *reinterpret_cast<const float4*>(&At[kk*36 + tm*4]);
      const float4 w0 = *reinterpret_cast<const float4*>(&Wt[kk*260 + tn*8]);
      const float4 w1 = *reinterpret_cast<const float4*>(&Wt[kk*260 + tn*8 + 4]);
      #pragma unroll
      for (int i = 0; i < 4; ++i) {
        const float ai = (&a.x)[i];
        acc[i][0]+=ai*w0.x; acc[i][1]+=ai*w0.y; acc[i][2]+=ai*w0.z; acc[i][3]+=ai*w0.w;
        acc[i][4]+=ai*w1.x; acc[i][5]+=ai*w1.y; acc[i][6]+=ai*w1.z; acc[i][7]+=ai*w1.w;
      }
    }
    av = avn;
    #pragma unroll
    for (int it = 0; it < 8; ++it) wv[it] = wvn[it];
  }
  const int na = n0 + tn*8, ma = m0 + tm*4;
  float bb[8];
  #pragma unroll
  for (int x = 0; x < 8; ++x) {
    if (WM == 0)      bb[x] = P.bias[na+x];
    else if (WM == 1) bb[x] = (na + x < HID) ? P.bias[na+x] : 0.f;
    else              bb[x] = 0.f;
  }
  #pragma unroll
  for (int i = 0; i < 4; ++i)
    #pragma unroll
    for (int x = 0; x < 8; ++x)
      P.C[(size_t)(ma+i)*P.ldc + na + x] = acc[i][x] + bb[x];
}

// ===== fp32 -> bf16 hi/lo split =====
__global__ __launch_bounds__(256) void cvt_k(const float* __restrict__ src,
                                             unsigned short* __restrict__ hi,
                                             unsigned short* __restrict__ lo, int n) {
  int i = (blockIdx.x*256 + threadIdx.x) * 4;
  const int stride = gridDim.x * 256 * 4;
  for (; i < n; i += stride) {
    const float4 v = ld4(src + i);
    us4 h, l;
    h.x = f2bf(v.x); l.x = f2bf(v.x - bf2f(h.x));
    h.y = f2bf(v.y); l.y = f2bf(v.y - bf2f(h.y));
    h.z = f2bf(v.z); l.z = f2bf(v.z - bf2f(h.z));
    h.w = f2bf(v.w); l.w = f2bf(v.w - bf2f(h.w));
    *reinterpret_cast<us4*>(hi + i) = h;
    *reinterpret_cast<us4*>(lo + i) = l;
  }
}

// ===== split-bf16 MFMA logits: out = AH·Wo^T + bo =====
struct LM {
  const unsigned short* Ahi; const unsigned short* Alo;
  const unsigned short* Bhi; const unsigned short* Blo;
  const float* bo; float* out;
};

__global__ __launch_bounds__(256) void logits_mfma(LM P) {
  __shared__ unsigned short sA[2][4][64][8];
  __shared__ unsigned short sB[2][4][128][8];
  const int tid = threadIdx.x;
  const int m0 = blockIdx.x * 64;
  const int n0 = blockIdx.y * 128;
  const int w = tid >> 6, l = tid & 63;
  const int mb = (w & 1) * 32, nb = (w >> 1) * 64;
  f32x4 acc[2][4];
  #pragma unroll
  for (int mt = 0; mt < 2; ++mt)
    #pragma unroll
    for (int nt = 0; nt < 4; ++nt) acc[mt][nt] = 0.f;

  const int arow = tid >> 2, akg = tid & 3;
  const int brow = tid >> 1, bkg = (tid & 1) * 2;
  short8 pah, pal, pbh0, pbh1, pbl0, pbl1;
  {
    const size_t ao = (size_t)(m0 + arow)*HID + akg*8;
    const size_t bo0 = (size_t)(n0 + brow)*HID + bkg*8;
    pah  = *reinterpret_cast<const short8*>(P.Ahi + ao);
    pal  = *reinterpret_cast<const short8*>(P.Alo + ao);
    pbh0 = *reinterpret_cast<const short8*>(P.Bhi + bo0);
    pbh1 = *reinterpret_cast<const short8*>(P.Bhi + bo0 + 8);
    pbl0 = *reinterpret_cast<const short8*>(P.Blo + bo0);
    pbl1 = *reinterpret_cast<const short8*>(P.Blo + bo0 + 8);
  }
  for (int kc = 0; kc < 32; ++kc) {
    __syncthreads();
    *reinterpret_cast<short8*>(&sA[0][akg][arow][0]) = pah;
    *reinterpret_cast<short8*>(&sA[1][akg][arow][0]) = pal;
    *reinterpret_cast<short8*>(&sB[0][bkg  ][brow][0]) = pbh0;
    *reinterpret_cast<short8*>(&sB[0][bkg+1][brow][0]) = pbh1;
    *reinterpret_cast<short8*>(&sB[1][bkg  ][brow][0]) = pbl0;
    *reinterpret_cast<short8*>(&sB[1][bkg+1][brow][0]) = pbl1;
    __syncthreads();
    if (kc + 1 < 32) {
      const size_t ao = (size_t)(m0 + arow)*HID + (kc+1)*32 + akg*8;
      const size_t bo0 = (size_t)(n0 + brow)*HID + (kc+1)*32 + bkg*8;
      pah  = *reinterpret_cast<const short8*>(P.Ahi + ao);
      pal  = *reinterpret_cast<const short8*>(P.Alo + ao);
      pbh0 = *reinterpret_cast<const short8*>(P.Bhi + bo0);
      pbh1 = *reinterpret_cast<const short8*>(P.Bhi + bo0 + 8);
      pbl0 = *reinterpret_cast<const short8*>(P.Blo + bo0);
      pbl1 = *reinterpret_cast<const short8*>(P.Blo + bo0 + 8);
    }
    const int kg = l >> 4, rr = l & 15;
    short8 ah[2], al[2];
    #pragma unroll
    for (int mt = 0; mt < 2; ++mt) {
      ah[mt] = *reinterpret_cast<const short8*>(&sA[0][kg][mb + mt*16 + rr][0]);
      al[mt] = *reinterpret_cast<const short8*>(&sA[1][kg][mb + mt*16 + rr][0]);
    }
    #pragma unroll
    for (int nt = 0; nt < 4; ++nt) {
      const short8 bh = *reinterpret_cast<const short8*>(&sB[0][kg][nb + nt*16 + rr][0]);
      const short8 bl = *reinterpret_cast<const short8*>(&sB[1][kg][nb + nt*16 + rr][0]);
      #pragma unroll
      for (int mt = 0; mt < 2; ++mt) {
        acc[mt][nt] = __builtin_amdgcn_mfma_f32_16x16x32_bf16(ah[mt], bh, acc[mt][nt], 0, 0, 0);
        acc[mt][nt] = __builtin_amdgcn_mfma_f32_16x16x32_bf16(ah[mt], bl, acc[mt][nt], 0, 0, 0);
        acc[mt][nt] = __builtin_amdgcn_mfma_f32_16x16x32_bf16(al[mt], bh, acc[mt][nt], 0, 0, 0);
      }
    }
  }
  #pragma unroll
  for (int mt = 0; mt < 2; ++mt) {
    #pragma unroll
    for (int nt = 0; nt < 4; ++nt) {
      #pragma unroll
      for (int r = 0; r < 4; ++r) {
        const int row = m0 + mb + mt*16 + (l >> 4)*4 + r;
        const int col = n0 + nb + nt*16 + (l & 15);
        if (row < NSTEP*BATCH)
          P.out[(size_t)row*VOCAB + col] = acc[mt][nt][r] + P.bo[col];
      }
    }
  }
}

// ===== per-(b,t) log-softmax + argmax =====
__global__ __launch_bounds__(256) void lsm_k(float* __restrict__ out,
                                             float* __restrict__ words) {
  const int b = blockIdx.x;
  const int t = blockIdx.y;
  float* row = out + ((size_t)t*BATCH + b)*VOCAB;
  const int tid = threadIdx.x;
  float m = -INFINITY; int mi = 0;
  for (int v = tid; v < VOCAB; v += 256) {
    const float x = row[v];
    if (x > m) { m = x; mi = v; }
  }
  __shared__ float sm[256]; __shared__ int si[256];
  sm[tid] = m; si[tid] = mi;
  __syncthreads();
  for (int s2 = 128; s2; s2 >>= 1) {
    if (tid < s2) {
      const float om = sm[tid+s2]; const int oi = si[tid+s2];
      if (om > sm[tid] || (om == sm[tid] && oi < si[tid])) { sm[tid]=om; si[tid]=oi; }
    }
    __syncthreads();
  }
  const float mx = sm[0]; const int amax = si[0];
  float s = 0.f;
  for (int v = tid; v < VOCAB; v += 256) s += expf(row[v]-mx);
  __shared__ float ss[256];
  ss[tid] = s; __syncthreads();
  for (int s2=128; s2; s2>>=1) { if (tid < s2) ss[tid] += ss[tid+s2]; __syncthreads(); }
  const float lse = logf(ss[0]) + mx;
  for (int v = tid; v < VOCAB; v += 256) row[v] = row[v] - lse;
  if (tid == 0) words[(size_t)t*BATCH + b] = (float)amax;
}

__global__ __launch_bounds__(256) void init_k(const float* __restrict__ enc_h,
                                              const float* __restrict__ enc_c,
                                              const float* __restrict__ bih0,
                                              const float* __restrict__ bhh0,
                                              const float* __restrict__ bih1,
                                              const float* __restrict__ bhh1,
                                              float* h0, float* h1, float* c0,
                                              float* c1, float* zbuf,
                                              float* bsum0, float* bsum1) {
  const int i = blockIdx.x*256 + threadIdx.x;
  if (i < BATCH*HID) {
    h0[i] = enc_h[i]; h1[i] = enc_h[BATCH*HID + i];
    c0[i] = enc_c[i]; c1[i] = enc_c[BATCH*HID + i];
    zbuf[i] = 0.f;
  }
  if (i < G4) {
    bsum0[i] = bih0[i] + bhh0[i];
    bsum1[i] = bih1[i] + bhh1[i];
  }
}

extern "C" void kernel_launch(void* const* d_in, const int* in_sizes, int n_in,
                              void* d_out, int out_size, void* d_ws, size_t ws_size,
                              hipStream_t stream) {
  const int*   tgt   = (const int*)d_in[0];
  const float* enc_h = (const float*)d_in[1];
  const float* enc_c = (const float*)d_in[2];
  const float* enc   = (const float*)d_in[3];
  const float* emb   = (const float*)d_in[4];
  const float* Wih0  = (const float*)d_in[5];
  const float* Whh0  = (const float*)d_in[6];
  const float* bih0  = (const float*)d_in[7];
  const float* bhh0  = (const float*)d_in[8];
  const float* Wih1  = (const float*)d_in[9];
  const float* Whh1  = (const float*)d_in[10];
  const float* bih1  = (const float*)d_in[11];
  const float* bhh1  = (const float*)d_in[12];
  const float* Wa    = (const float*)d_in[13];
  const float* ba    = (const float*)d_in[14];
  const float* va    = (const float*)d_in[15];
  const float* Wc    = (const float*)d_in[16];
  const float* bc    = (const float*)d_in[17];
  const float* Wo    = (const float*)d_in[18];
  const float* bo    = (const float*)d_in[19];

  float* ws = (float*)d_ws;
  // AH lives through the epilogue; everything after it is a pool that the
  // bf16 buffers overlay once the loop is done.
  float* AH = ws;                                     // [2048,1024]
  float* pool = AH + (size_t)2048*1024;
  size_t off = 0;
  auto alloc = [&](size_t n) { float* p = pool + off; off += n; return p; };
  float* PreAC = alloc((size_t)2048*2048);
  float* Pq    = alloc((size_t)BATCH*2048);
  float* PgH0  = alloc((size_t)BATCH*G4);
  float* PgH1  = alloc((size_t)BATCH*G4);
  float* h0    = alloc(BATCH*HID);
  float* h1v   = alloc(BATCH*HID);
  float* c0    = alloc(BATCH*HID);
  float* c1v   = alloc(BATCH*HID);
  float* zbuf  = alloc(BATCH*HID);
  float* bsum0 = alloc(G4);
  float* bsum1 = alloc(G4);
  float* Gemb  = pool + off;
  const size_t loop_f = (size_t)(pool - ws) + off + (size_t)NSTEP*BATCH*G4;
  const bool hoist = ws_size >= loop_f * sizeof(float);

  const size_t nAH = (size_t)2048*1024, nWo = (size_t)VOCAB*1024;
  unsigned short* AHhi = (unsigned short*)pool;       // overlays loop scratch (dead post-loop)
  unsigned short* AHlo = AHhi + nAH;
  unsigned short* Wohi = AHlo + nAH;
  unsigned short* Wolo = Wohi + nWo;
  const bool mfma_ok =
      ws_size >= (size_t)2048*1024*sizeof(float) + (2*nAH + 2*nWo)*sizeof(unsigned short);

  float* out   = (float*)d_out;
  float* words = out + (size_t)NSTEP*BATCH*VOCAB;

  init_k<<<dim3(128), 256, 0, stream>>>(enc_h, enc_c, bih0, bhh0, bih1, bhh1,
                                        h0, h1v, c0, c1v, zbuf, bsum0, bsum1);

  { // PreAC = enc @ [Wa2; Wc2]^T + [ba; 0]
    WGP p = {}; p.A = enc; p.W = Wa; p.W2 = Wc; p.bias = ba; p.C = PreAC; p.ldc = 2048;
    gemmL<1><<<dim3(64, 8), 256, 0, stream>>>(p);
  }
  if (hoist) { // Gemb = emb[tok] @ Wih0[:, :512]^T for all (t,b)
    WGP p = {}; p.W = Wih0; p.tgt = tgt; p.emb = emb; p.C = Gemb; p.ldc = G4;
    gemmL<2><<<dim3(NSTEP*BATCH/32, G4/256), 256, 0, stream>>>(p);
  }
  { // PgH0/PgH1 from initial h
    WIP p; p.h0 = h0; p.h1 = h1v; p.Whh0 = Whh0; p.Whh1 = Whh1;
    p.PgH0 = PgH0; p.PgH1 = PgH1;
    whhinit_k<<<dim3(256), 1024, 0, stream>>>(p);
  }

  for (int t = 0; t < NSTEP; ++t) {
    const float* ah_prev = t ? (AH + (size_t)(t-1)*BATCH*HID) : zbuf;
    { // L1: gates0 + cell0
      GC p = {}; p.tgt = tgt; p.emb = emb; p.t = t;
      p.A = ah_prev; p.W = Wih0;
      p.gembt = Gemb + (size_t)t*BATCH*G4;
      p.PgH = PgH0; p.bsum = bsum0; p.h = h0; p.c = c0;
      if (hoist) l1_k<1><<<dim3(128), 1024, 0, stream>>>(p);
      else       l1_k<0><<<dim3(128), 1024, 0, stream>>>(p);
    }
    { // L2: gates1 + cell1 ∥ Whh0·h0_t -> PgH0 (for t+1)
      L2P p = {};
      p.gc.A = h0; p.gc.W = Wih1; p.gc.PgH = PgH1; p.gc.bsum = bsum1;
      p.gc.h = h1v; p.gc.c = c1v; p.gc.t = t;
      p.h0 = h0; p.Whh0 = Whh0; p.PgH0 = PgH0;
      l2_k<<<dim3(256), 1024, 0, stream>>>(p);
    }
    { // L3: Pq = h1·[Wa1;Wc1]^T
      L3P p; p.h1 = h1v; p.Wa = Wa; p.Wc = Wc; p.Pq = Pq;
      l3_k<<<dim3(64), 1024, 0, stream>>>(p);
    }
    { // L4: attention -> AH[t] ∥ Whh1·h1_t -> PgH1 (for t+1)
      L4P p; p.Pq = Pq; p.PreAC = PreAC; p.va = va; p.bc = bc;
      p.h1 = h1v; p.Whh1 = Whh1;
      p.AHt = AH + (size_t)t*BATCH*HID; p.PgH1 = PgH1;
      l4_k<<<dim3(160), 1024, 0, stream>>>(p);
    }
  }

  if (mfma_ok) {
    cvt_k<<<dim3(4096), 256, 0, stream>>>(Wo, Wohi, Wolo, VOCAB*1024);
    cvt_k<<<dim3(2048), 256, 0, stream>>>(AH, AHhi, AHlo, NSTEP*BATCH*HID);
    LM p; p.Ahi = AHhi; p.Alo = AHlo; p.Bhi = Wohi; p.Blo = Wolo;
    p.bo = bo; p.out = out;
    logits_mfma<<<dim3(32, VOCAB/128), 256, 0, stream>>>(p);
  } else {
    WGP p = {}; p.A = AH; p.W = Wo; p.bias = bo; p.C = out; p.ldc = VOCAB;
    gemmL<0><<<dim3(NSTEP*BATCH/32, VOCAB/256), 256, 0, stream>>>(p);
  }
  lsm_k<<<dim3(BATCH, NSTEP), 256, 0, stream>>>(out, words);
}

// Round 11
// 5913.942 us; speedup vs baseline: 3.6283x; 1.1958x over previous
//
#include <hip/hip_runtime.h>
#include <math.h>

#define VOCAB 32000
#define EMBD  512
#define HID   1024
#define BATCH 32
#define SEQ   64
#define TENC  64
#define NSTEP 63
#define G4    4096

typedef __attribute__((ext_vector_type(8))) short short8;
typedef __attribute__((ext_vector_type(4))) float f32x4;
typedef __attribute__((ext_vector_type(4))) unsigned short us4;
typedef unsigned short u16;

__device__ __forceinline__ float4 ld4(const float* p) {
  return *reinterpret_cast<const float4*>(p);
}
__device__ __forceinline__ u16 f2bf(float x) {
  unsigned u = __float_as_uint(x);
  return (u16)((u + 0x7fffu + ((u >> 16) & 1u)) >> 16);
}
__device__ __forceinline__ float bf2f(u16 h) {
  return __uint_as_float(((unsigned)h) << 16);
}

// ===== MFMA 32x32 tile core: C[32b][32r] = X·W^T, split-bf16 (hi+lo, 3 mfma) =====
// 256-thr block = 4 waves, K-split by wave; partials -> res[4][32][33] fp32.
// MODE 0: K=2048, X=[Xa|Xb] (each [32][1024]), W rows local r -> g*1024+nt*8+(r&7), stride 2048
// MODE 1: K=1024, X=Xa, W rows nt*32+r, stride 1024
template<int MODE>
__device__ __forceinline__ void mfma32(
    const u16* __restrict__ Xahi, const u16* __restrict__ Xalo,
    const u16* __restrict__ Xbhi, const u16* __restrict__ Xblo,
    const u16* __restrict__ Whi,  const u16* __restrict__ Wlo,
    int nt, float* res)
{
  const int tid = threadIdx.x;
  const int w = tid >> 6, l = tid & 63;
  const int c = l & 15, koct = l >> 4;
  constexpr int K   = (MODE == 0) ? 2048 : 1024;
  constexpr int WS  = (MODE == 0) ? 2048 : 1024;
  constexpr int SPW = K / 32 / 4;                   // k-steps per wave
  const int r0 = c, r1 = 16 + c;
  const int wr0 = (MODE == 0) ? ((r0 >> 3)*1024 + nt*8 + (r0 & 7)) : (nt*32 + r0);
  const int wr1 = (MODE == 0) ? ((r1 >> 3)*1024 + nt*8 + (r1 & 7)) : (nt*32 + r1);
  const u16* bh0 = Whi + (size_t)wr0 * WS;
  const u16* bh1 = Whi + (size_t)wr1 * WS;
  const u16* bl0 = Wlo + (size_t)wr0 * WS;
  const u16* bl1 = Wlo + (size_t)wr1 * WS;

  auto ldA = [&](int m, int kg, int lo) -> short8 {
    const u16* base;
    if (MODE == 0 && kg >= 1024) base = lo ? Xblo : Xbhi;
    else                         base = lo ? Xalo : Xahi;
    const int b = m*16 + c;
    return *reinterpret_cast<const short8*>(base + b*1024 + (kg & 1023));
  };

  f32x4 acc[2][2];
  #pragma unroll
  for (int m = 0; m < 2; ++m)
    #pragma unroll
    for (int n = 0; n < 2; ++n) acc[m][n] = (f32x4){0.f,0.f,0.f,0.f};

  const int s0 = w * SPW;
  short8 Ah[2], Al[2], Bh[2], Bl[2];
  {
    const int kg = s0*32 + koct*8;
    Ah[0]=ldA(0,kg,0); Ah[1]=ldA(1,kg,0); Al[0]=ldA(0,kg,1); Al[1]=ldA(1,kg,1);
    Bh[0]=*reinterpret_cast<const short8*>(bh0+kg);
    Bh[1]=*reinterpret_cast<const short8*>(bh1+kg);
    Bl[0]=*reinterpret_cast<const short8*>(bl0+kg);
    Bl[1]=*reinterpret_cast<const short8*>(bl1+kg);
  }
  for (int s = s0; s < s0 + SPW; ++s) {
    short8 nAh[2], nAl[2], nBh[2], nBl[2];
    if (s + 1 < s0 + SPW) {
      const int kg = (s+1)*32 + koct*8;
      nAh[0]=ldA(0,kg,0); nAh[1]=ldA(1,kg,0); nAl[0]=ldA(0,kg,1); nAl[1]=ldA(1,kg,1);
      nBh[0]=*reinterpret_cast<const short8*>(bh0+kg);
      nBh[1]=*reinterpret_cast<const short8*>(bh1+kg);
      nBl[0]=*reinterpret_cast<const short8*>(bl0+kg);
      nBl[1]=*reinterpret_cast<const short8*>(bl1+kg);
    }
    #pragma unroll
    for (int n = 0; n < 2; ++n)
      #pragma unroll
      for (int m = 0; m < 2; ++m) {
        acc[m][n] = __builtin_amdgcn_mfma_f32_16x16x32_bf16(Ah[m], Bh[n], acc[m][n], 0, 0, 0);
        acc[m][n] = __builtin_amdgcn_mfma_f32_16x16x32_bf16(Ah[m], Bl[n], acc[m][n], 0, 0, 0);
        acc[m][n] = __builtin_amdgcn_mfma_f32_16x16x32_bf16(Al[m], Bh[n], acc[m][n], 0, 0, 0);
      }
    #pragma unroll
    for (int i = 0; i < 2; ++i) { Ah[i]=nAh[i]; Al[i]=nAl[i]; Bh[i]=nBh[i]; Bl[i]=nBl[i]; }
  }
  // C layout: col = lane&15, row = (lane>>4)*4 + reg  (validated via logits_mfma)
  #pragma unroll
  for (int m = 0; m < 2; ++m)
    #pragma unroll
    for (int n = 0; n < 2; ++n)
      #pragma unroll
      for (int r = 0; r < 4; ++r) {
        const int b = m*16 + koct*4 + r;
        const int rr = n*16 + c;
        res[w*1056 + b*33 + rr] = acc[m][n][r];
      }
}

// ===== gates (K=2048 concat) + block-local LSTM cell; h out as bf16 hi/lo =====
struct GKM {
  const u16 *Xahi, *Xalo, *Xbhi, *Xblo;     // [ah|h0] or [h0|h1prev]
  const u16 *Whi, *Wlo;                     // packed [4096][2048]
  const float* bsum; const float* gembt;    // gembt only L1
  float* c; u16 *hhi; u16 *hlo;
};

template<int HASGEMB>
__global__ __launch_bounds__(256) void gates_mfma_k(GKM P) {
  __shared__ float res[4*1056];
  mfma32<0>(P.Xahi, P.Xalo, P.Xbhi, P.Xblo, P.Whi, P.Wlo, blockIdx.x, res);
  __syncthreads();
  const int tid = threadIdx.x;
  const int b = tid >> 3, j = tid & 7;
  const int n = blockIdx.x*8 + j;
  float g4[4];
  #pragma unroll
  for (int g = 0; g < 4; ++g) {
    const int r = g*8 + j;
    float s = P.bsum[g*1024 + n]
            + res[b*33+r] + res[1056 + b*33+r] + res[2112 + b*33+r] + res[3168 + b*33+r];
    if (HASGEMB) s += P.gembt[(size_t)b*G4 + g*1024 + n];
    g4[g] = s;
  }
  const float si = 1.f/(1.f+expf(-g4[0]));
  const float sf = 1.f/(1.f+expf(-g4[1]));
  const float so = 1.f/(1.f+expf(-g4[3]));
  const int i = b*HID + n;
  const float cn = sf*P.c[i] + si*tanhf(g4[2]);
  P.c[i] = cn;
  const float h = so*tanhf(cn);
  const u16 hh = f2bf(h);
  P.hhi[i] = hh;
  P.hlo[i] = f2bf(h - bf2f(hh));
}

// ===== proj: Pq[32][2048] = h1 · [Wa1;Wc1]^T (fp32 out) =====
struct PKM {
  const u16 *Xhi, *Xlo; const u16 *Whi, *Wlo; float* Pq;
};

__global__ __launch_bounds__(256) void proj_mfma_k(PKM P) {
  __shared__ float res[4*1056];
  mfma32<1>(P.Xhi, P.Xlo, nullptr, nullptr, P.Whi, P.Wlo, blockIdx.x, res);
  __syncthreads();
  const int tid = threadIdx.x;
  #pragma unroll
  for (int q = 0; q < 4; ++q) {
    const int o = q*256 + tid;
    const int b = o >> 5, r = o & 31;
    const float s = res[b*33+r] + res[1056 + b*33+r]
                  + res[2112 + b*33+r] + res[3168 + b*33+r];
    P.Pq[(size_t)b*2048 + blockIdx.x*32 + r] = s;
  }
}

// ===== attn: 32 blocks x 1024 thr; writes AH[t] as bf16 hi/lo =====
struct AKM {
  const float* Pq; const float* PreAC; const float* va; const float* bc;
  u16* AHthi; u16* AHtlo;
};

__global__ __launch_bounds__(1024) void attn_k(AKM P) {
  __shared__ float QS[HID];
  __shared__ float sw[TENC];
  __shared__ float W64[TENC];
  const int b = blockIdx.x;
  const int tid = threadIdx.x;
  QS[tid] = P.Pq[(size_t)b*2048 + tid];
  __syncthreads();
  const int lane = tid & 63, wid = tid >> 6;    // 16 waves
  float vreg[16];
  #pragma unroll
  for (int i2 = 0; i2 < 16; ++i2) vreg[i2] = P.va[lane + 64*i2];
  #pragma unroll
  for (int j = 0; j < 4; ++j) {
    const int te = wid*4 + j;
    const float* pr = P.PreAC + ((size_t)te*BATCH + b)*2048;
    float s = 0.f;
    #pragma unroll
    for (int i2 = 0; i2 < 16; ++i2) {
      const int idx = lane + 64*i2;
      s += vreg[i2] * tanhf(QS[idx] + pr[idx]);
    }
    #pragma unroll
    for (int off = 32; off; off >>= 1) s += __shfl_xor(s, off);
    if (lane == 0) sw[te] = s;
  }
  __syncthreads();
  if (tid < TENC) {
    const float v = sw[tid];
    float mx = v;
    #pragma unroll
    for (int off = 32; off; off >>= 1) mx = fmaxf(mx, __shfl_xor(mx, off));
    const float e = expf(v - mx);
    float sum = e;
    #pragma unroll
    for (int off = 32; off; off >>= 1) sum += __shfl_xor(sum, off);
    W64[tid] = e / sum;
  }
  __syncthreads();
  const int hh = tid;
  float acc = 0.f;
  #pragma unroll 8
  for (int te = 0; te < TENC; ++te)
    acc += W64[te] * P.PreAC[((size_t)te*BATCH + b)*2048 + HID + hh];
  const float hc = P.Pq[(size_t)b*2048 + HID + hh] + P.bc[hh];
  const float ah = tanhf(acc + hc);
  const u16 ahh = f2bf(ah);
  P.AHthi[(size_t)b*HID + hh] = ahh;
  P.AHtlo[(size_t)b*HID + hh] = f2bf(ah - bf2f(ahh));
}

// ===== weight pack + hi/lo split (one-time) =====
// MODE0: [4096][2048] <- [Wih0[:,512:1536] | Whh0] ; MODE1: <- [Wih1 | Whh1]
// MODE2: [2048][1024] <- rows: Wa[0:1024][0:1024], Wc[0:1024][0:1024] (stride 2048)
template<int MODE>
__global__ __launch_bounds__(256) void pack_k(const float* __restrict__ A,
                                              const float* __restrict__ B,
                                              u16* __restrict__ hi, u16* __restrict__ lo) {
  constexpr int ROWS = (MODE == 2) ? 2048 : 4096;
  constexpr int K    = (MODE == 2) ? 1024 : 2048;
  const size_t total = (size_t)ROWS * (K/4);
  for (size_t i = (size_t)blockIdx.x*256 + threadIdx.x; i < total;
       i += (size_t)gridDim.x*256) {
    const int row = (int)(i / (K/4));
    const int k = (int)(i % (K/4)) * 4;
    float4 v;
    if (MODE == 0) v = (k < 1024) ? ld4(A + (size_t)row*1536 + 512 + k)
                                  : ld4(B + (size_t)row*1024 + (k - 1024));
    else if (MODE == 1) v = (k < 1024) ? ld4(A + (size_t)row*1024 + k)
                                       : ld4(B + (size_t)row*1024 + (k - 1024));
    else v = (row < 1024) ? ld4(A + (size_t)row*2048 + k)
                          : ld4(B + (size_t)(row - 1024)*2048 + k);
    us4 h, l;
    h.x = f2bf(v.x); l.x = f2bf(v.x - bf2f(h.x));
    h.y = f2bf(v.y); l.y = f2bf(v.y - bf2f(h.y));
    h.z = f2bf(v.z); l.z = f2bf(v.z - bf2f(h.z));
    h.w = f2bf(v.w); l.w = f2bf(v.w - bf2f(h.w));
    *reinterpret_cast<us4*>(hi + i*4) = h;
    *reinterpret_cast<us4*>(lo + i*4) = l;
  }
}

// ===== fp32 -> bf16 hi/lo (for Wo) =====
__global__ __launch_bounds__(256) void cvt_k(const float* __restrict__ src,
                                             u16* __restrict__ hi,
                                             u16* __restrict__ lo, int n) {
  int i = (blockIdx.x*256 + threadIdx.x) * 4;
  const int stride = gridDim.x * 256 * 4;
  for (; i < n; i += stride) {
    const float4 v = ld4(src + i);
    us4 h, l;
    h.x = f2bf(v.x); l.x = f2bf(v.x - bf2f(h.x));
    h.y = f2bf(v.y); l.y = f2bf(v.y - bf2f(h.y));
    h.z = f2bf(v.z); l.z = f2bf(v.z - bf2f(h.z));
    h.w = f2bf(v.w); l.w = f2bf(v.w - bf2f(h.w));
    *reinterpret_cast<us4*>(hi + i) = h;
    *reinterpret_cast<us4*>(lo + i) = l;
  }
}

// ===== fp32 wide GEMM (PreAC / Gemb) =====
struct WGP {
  const float* A; const float* W; const float* W2; const float* bias;
  const int* tgt; const float* emb;
  float* C; int ldc;
};

template<int WM>
__device__ __forceinline__ float4 ldWL(const WGP& P, int r, int k) {
  if (WM == 2) return ld4(P.W + (size_t)r * (EMBD + HID) + k);
  if (r < HID) return ld4(P.W  + (size_t)r * (2*HID) + HID + k);
  return ld4(P.W2 + (size_t)(r - HID) * (2*HID) + HID + k);
}

template<int WM>
__device__ __forceinline__ float4 ldAL(const WGP& P, int row, int k) {
  if (WM == 2) {
    const int tok = P.tgt[(row & 31) * SEQ + (row >> 5)];
    return ld4(P.emb + (size_t)tok * EMBD + k);
  }
  return ld4(P.A + (size_t)row * 1024 + k);
}

template<int WM>
__global__ __launch_bounds__(256, 2) void gemmL(WGP P) {
  constexpr int KK = (WM == 2) ? 512 : 1024;
  __shared__ float At[32*36];
  __shared__ float Wt[32*260];
  const int tid = threadIdx.x;
  const int m0 = blockIdx.x * 32;
  const int n0 = blockIdx.y * 256;
  const int lr = tid >> 3, lc = (tid & 7) << 2;
  const int tn = tid & 31, tm = tid >> 5;
  float acc[4][8];
  #pragma unroll
  for (int i = 0; i < 4; ++i)
    #pragma unroll
    for (int x = 0; x < 8; ++x) acc[i][x] = 0.f;

  float4 av = ldAL<WM>(P, m0 + lr, lc);
  float4 wv[8];
  #pragma unroll
  for (int it = 0; it < 8; ++it) wv[it] = ldWL<WM>(P, n0 + lr + it*32, lc);

  for (int k0 = 0; k0 < KK; k0 += 32) {
    float4 avn, wvn[8];
    if (k0 + 32 < KK) {
      avn = ldAL<WM>(P, m0 + lr, k0 + 32 + lc);
      #pragma unroll
      for (int it = 0; it < 8; ++it) wvn[it] = ldWL<WM>(P, n0 + lr + it*32, k0 + 32 + lc);
    }
    __syncthreads();
    At[(lc+0)*36+lr]=av.x; At[(lc+1)*36+lr]=av.y; At[(lc+2)*36+lr]=av.z; At[(lc+3)*36+lr]=av.w;
    #pragma unroll
    for (int it = 0; it < 8; ++it) {
      const int r = lr + it*32;
      Wt[(lc+0)*260+r]=wv[it].x; Wt[(lc+1)*260+r]=wv[it].y;
      Wt[(lc+2)*260+r]=wv[it].z; Wt[(lc+3)*260+r]=wv[it].w;
    }
    __syncthreads();
    #pragma unroll
    for (int kk = 0; kk < 32; ++kk) {
      const float4 a  = *reinterpret_cast<const float4*>(&At[kk*36 + tm*4]);
      const float4 w0 = *reinterpret_cast<const float4*>(&Wt[kk*260 + tn*8]);
      const float4 w1 = *reinterpret_cast<const float4*>(&Wt[kk*260 + tn*8 + 4]);
      #pragma unroll
      for (int i = 0; i < 4; ++i) {
        const float ai = (&a.x)[i];
        acc[i][0]+=ai*w0.x; acc[i][1]+=ai*w0.y; acc[i][2]+=ai*w0.z; acc[i][3]+=ai*w0.w;
        acc[i][4]+=ai*w1.x; acc[i][5]+=ai*w1.y; acc[i][6]+=ai*w1.z; acc[i][7]+=ai*w1.w;
      }
    }
    av = avn;
    #pragma unroll
    for (int it = 0; it < 8; ++it) wv[it] = wvn[it];
  }
  const int na = n0 + tn*8, ma = m0 + tm*4;
  float bb[8];
  #pragma unroll
  for (int x = 0; x < 8; ++x) {
    if (WM == 1) bb[x] = (na + x < HID) ? P.bias[na+x] : 0.f;
    else         bb[x] = 0.f;
  }
  #pragma unroll
  for (int i = 0; i < 4; ++i)
    #pragma unroll
    for (int x = 0; x < 8; ++x)
      P.C[(size_t)(ma+i)*P.ldc + na + x] = acc[i][x] + bb[x];
}

// ===== split-bf16 MFMA logits: out = AH·Wo^T + bo =====
struct LM {
  const u16* Ahi; const u16* Alo;
  const u16* Bhi; const u16* Blo;
  const float* bo; float* out;
};

__global__ __launch_bounds__(256) void logits_mfma(LM P) {
  __shared__ u16 sA[2][4][64][8];
  __shared__ u16 sB[2][4][128][8];
  const int tid = threadIdx.x;
  const int m0 = blockIdx.x * 64;
  const int n0 = blockIdx.y * 128;
  const int w = tid >> 6, l = tid & 63;
  const int mb = (w & 1) * 32, nb = (w >> 1) * 64;
  f32x4 acc[2][4];
  #pragma unroll
  for (int mt = 0; mt < 2; ++mt)
    #pragma unroll
    for (int nt = 0; nt < 4; ++nt) acc[mt][nt] = (f32x4){0.f,0.f,0.f,0.f};

  const int arow = tid >> 2, akg = tid & 3;
  const int brow = tid >> 1, bkg = (tid & 1) * 2;
  short8 pah, pal, pbh0, pbh1, pbl0, pbl1;
  {
    const size_t ao = (size_t)(m0 + arow)*HID + akg*8;
    const size_t bo0 = (size_t)(n0 + brow)*HID + bkg*8;
    pah  = *reinterpret_cast<const short8*>(P.Ahi + ao);
    pal  = *reinterpret_cast<const short8*>(P.Alo + ao);
    pbh0 = *reinterpret_cast<const short8*>(P.Bhi + bo0);
    pbh1 = *reinterpret_cast<const short8*>(P.Bhi + bo0 + 8);
    pbl0 = *reinterpret_cast<const short8*>(P.Blo + bo0);
    pbl1 = *reinterpret_cast<const short8*>(P.Blo + bo0 + 8);
  }
  for (int kc = 0; kc < 32; ++kc) {
    __syncthreads();
    *reinterpret_cast<short8*>(&sA[0][akg][arow][0]) = pah;
    *reinterpret_cast<short8*>(&sA[1][akg][arow][0]) = pal;
    *reinterpret_cast<short8*>(&sB[0][bkg  ][brow][0]) = pbh0;
    *reinterpret_cast<short8*>(&sB[0][bkg+1][brow][0]) = pbh1;
    *reinterpret_cast<short8*>(&sB[1][bkg  ][brow][0]) = pbl0;
    *reinterpret_cast<short8*>(&sB[1][bkg+1][brow][0]) = pbl1;
    __syncthreads();
    if (kc + 1 < 32) {
      const size_t ao = (size_t)(m0 + arow)*HID + (kc+1)*32 + akg*8;
      const size_t bo0 = (size_t)(n0 + brow)*HID + (kc+1)*32 + bkg*8;
      pah  = *reinterpret_cast<const short8*>(P.Ahi + ao);
      pal  = *reinterpret_cast<const short8*>(P.Alo + ao);
      pbh0 = *reinterpret_cast<const short8*>(P.Bhi + bo0);
      pbh1 = *reinterpret_cast<const short8*>(P.Bhi + bo0 + 8);
      pbl0 = *reinterpret_cast<const short8*>(P.Blo + bo0);
      pbl1 = *reinterpret_cast<const short8*>(P.Blo + bo0 + 8);
    }
    const int kg = l >> 4, rr = l & 15;
    short8 ah[2], al[2];
    #pragma unroll
    for (int mt = 0; mt < 2; ++mt) {
      ah[mt] = *reinterpret_cast<const short8*>(&sA[0][kg][mb + mt*16 + rr][0]);
      al[mt] = *reinterpret_cast<const short8*>(&sA[1][kg][mb + mt*16 + rr][0]);
    }
    #pragma unroll
    for (int nt = 0; nt < 4; ++nt) {
      const short8 bh = *reinterpret_cast<const short8*>(&sB[0][kg][nb + nt*16 + rr][0]);
      const short8 bl = *reinterpret_cast<const short8*>(&sB[1][kg][nb + nt*16 + rr][0]);
      #pragma unroll
      for (int mt = 0; mt < 2; ++mt) {
        acc[mt][nt] = __builtin_amdgcn_mfma_f32_16x16x32_bf16(ah[mt], bh, acc[mt][nt], 0, 0, 0);
        acc[mt][nt] = __builtin_amdgcn_mfma_f32_16x16x32_bf16(ah[mt], bl, acc[mt][nt], 0, 0, 0);
        acc[mt][nt] = __builtin_amdgcn_mfma_f32_16x16x32_bf16(al[mt], bh, acc[mt][nt], 0, 0, 0);
      }
    }
  }
  #pragma unroll
  for (int mt = 0; mt < 2; ++mt) {
    #pragma unroll
    for (int nt = 0; nt < 4; ++nt) {
      #pragma unroll
      for (int r = 0; r < 4; ++r) {
        const int row = m0 + mb + mt*16 + (l >> 4)*4 + r;
        const int col = n0 + nb + nt*16 + (l & 15);
        if (row < NSTEP*BATCH)
          P.out[(size_t)row*VOCAB + col] = acc[mt][nt][r] + P.bo[col];
      }
    }
  }
}

// ===== per-(b,t) log-softmax + argmax =====
__global__ __launch_bounds__(256) void lsm_k(float* __restrict__ out,
                                             float* __restrict__ words) {
  const int b = blockIdx.x;
  const int t = blockIdx.y;
  float* row = out + ((size_t)t*BATCH + b)*VOCAB;
  const int tid = threadIdx.x;
  float m = -INFINITY; int mi = 0;
  for (int v = tid; v < VOCAB; v += 256) {
    const float x = row[v];
    if (x > m) { m = x; mi = v; }
  }
  __shared__ float sm[256]; __shared__ int si[256];
  sm[tid] = m; si[tid] = mi;
  __syncthreads();
  for (int s2 = 128; s2; s2 >>= 1) {
    if (tid < s2) {
      const float om = sm[tid+s2]; const int oi = si[tid+s2];
      if (om > sm[tid] || (om == sm[tid] && oi < si[tid])) { sm[tid]=om; si[tid]=oi; }
    }
    __syncthreads();
  }
  const float mx = sm[0]; const int amax = si[0];
  float s = 0.f;
  for (int v = tid; v < VOCAB; v += 256) s += expf(row[v]-mx);
  __shared__ float ss[256];
  ss[tid] = s; __syncthreads();
  for (int s2=128; s2; s2>>=1) { if (tid < s2) ss[tid] += ss[tid+s2]; __syncthreads(); }
  const float lse = logf(ss[0]) + mx;
  for (int v = tid; v < VOCAB; v += 256) row[v] = row[v] - lse;
  if (tid == 0) words[(size_t)t*BATCH + b] = (float)amax;
}

// ===== init: c0/c1 fp32; h0/h1/zah as bf16 hi/lo; bias sums =====
__global__ __launch_bounds__(256) void init_k(const float* __restrict__ enc_h,
                                              const float* __restrict__ enc_c,
                                              const float* __restrict__ bih0,
                                              const float* __restrict__ bhh0,
                                              const float* __restrict__ bih1,
                                              const float* __restrict__ bhh1,
                                              float* c0, float* c1,
                                              u16* h0hi, u16* h0lo, u16* h1hi, u16* h1lo,
                                              u16* zahhi, u16* zahlo,
                                              float* bsum0, float* bsum1) {
  const int i = blockIdx.x*256 + threadIdx.x;
  if (i < BATCH*HID) {
    c0[i] = enc_c[i]; c1[i] = enc_c[BATCH*HID + i];
    const float v0 = enc_h[i];
    const u16 h0 = f2bf(v0);
    h0hi[i] = h0; h0lo[i] = f2bf(v0 - bf2f(h0));
    const float v1 = enc_h[BATCH*HID + i];
    const u16 h1 = f2bf(v1);
    h1hi[i] = h1; h1lo[i] = f2bf(v1 - bf2f(h1));
    zahhi[i] = 0; zahlo[i] = 0;
  }
  if (i < G4) {
    bsum0[i] = bih0[i] + bhh0[i];
    bsum1[i] = bih1[i] + bhh1[i];
  }
}

extern "C" void kernel_launch(void* const* d_in, const int* in_sizes, int n_in,
                              void* d_out, int out_size, void* d_ws, size_t ws_size,
                              hipStream_t stream) {
  const int*   tgt   = (const int*)d_in[0];
  const float* enc_h = (const float*)d_in[1];
  const float* enc_c = (const float*)d_in[2];
  const float* enc   = (const float*)d_in[3];
  const float* emb   = (const float*)d_in[4];
  const float* Wih0  = (const float*)d_in[5];
  const float* Whh0  = (const float*)d_in[6];
  const float* bih0  = (const float*)d_in[7];
  const float* bhh0  = (const float*)d_in[8];
  const float* Wih1  = (const float*)d_in[9];
  const float* Whh1  = (const float*)d_in[10];
  const float* bih1  = (const float*)d_in[11];
  const float* bhh1  = (const float*)d_in[12];
  const float* Wa    = (const float*)d_in[13];
  const float* ba    = (const float*)d_in[14];
  const float* va    = (const float*)d_in[15];
  const float* Wc    = (const float*)d_in[16];
  const float* bc    = (const float*)d_in[17];
  const float* Wo    = (const float*)d_in[18];
  const float* bo    = (const float*)d_in[19];

  // Layout: [AHhi | AHlo | pool]; pool holds loop-only data, overlaid by Wo hi/lo post-loop.
  u16* AHhi = (u16*)d_ws;                                // [2048][1024]
  u16* AHlo = AHhi + (size_t)2048*1024;
  float* pool = (float*)(AHlo + (size_t)2048*1024);

  float* PreAC = pool;                                   // [2048][2048]
  float* Gemb  = PreAC + (size_t)2048*2048;              // [2016][4096]
  float* Pq    = Gemb  + (size_t)NSTEP*BATCH*G4;         // [32][2048]
  float* c0    = Pq    + (size_t)BATCH*2048;
  float* c1v   = c0    + BATCH*HID;
  float* bsum0 = c1v   + BATCH*HID;
  float* bsum1 = bsum0 + G4;
  u16* W0hi = (u16*)(bsum1 + G4);                        // [4096][2048]
  u16* W0lo = W0hi + (size_t)4096*2048;
  u16* W1hi = W0lo + (size_t)4096*2048;                  // [4096][2048]
  u16* W1lo = W1hi + (size_t)4096*2048;
  u16* WAhi = W1lo + (size_t)4096*2048;                  // [2048][1024]
  u16* WAlo = WAhi + (size_t)2048*1024;
  u16* h0Ahi = WAlo + (size_t)2048*1024;                 // 10 x [32][1024]
  u16* h0Alo = h0Ahi + BATCH*HID;
  u16* h0Bhi = h0Alo + BATCH*HID;
  u16* h0Blo = h0Bhi + BATCH*HID;
  u16* h1Ahi = h0Blo + BATCH*HID;
  u16* h1Alo = h1Ahi + BATCH*HID;
  u16* h1Bhi = h1Alo + BATCH*HID;
  u16* h1Blo = h1Bhi + BATCH*HID;
  u16* zahhi = h1Blo + BATCH*HID;
  u16* zahlo = zahhi + BATCH*HID;
  // post-loop overlay (loop scratch is dead):
  u16* Wohi = (u16*)pool;                                // [32000][1024]
  u16* Wolo = Wohi + (size_t)VOCAB*1024;

  float* out   = (float*)d_out;
  float* words = out + (size_t)NSTEP*BATCH*VOCAB;

  init_k<<<dim3(128), 256, 0, stream>>>(enc_h, enc_c, bih0, bhh0, bih1, bhh1,
                                        c0, c1v, h0Ahi, h0Alo, h1Ahi, h1Alo,
                                        zahhi, zahlo, bsum0, bsum1);

  { // PreAC = enc @ [Wa2; Wc2]^T + [ba; 0]
    WGP p = {}; p.A = enc; p.W = Wa; p.W2 = Wc; p.bias = ba; p.C = PreAC; p.ldc = 2048;
    gemmL<1><<<dim3(64, 8), 256, 0, stream>>>(p);
  }
  { // Gemb = emb[tok] @ Wih0[:, :512]^T for all (t,b)
    WGP p = {}; p.W = Wih0; p.tgt = tgt; p.emb = emb; p.C = Gemb; p.ldc = G4;
    gemmL<2><<<dim3(NSTEP*BATCH/32, G4/256), 256, 0, stream>>>(p);
  }
  // weight packs (one-time)
  pack_k<0><<<dim3(1024), 256, 0, stream>>>(Wih0, Whh0, W0hi, W0lo);
  pack_k<1><<<dim3(1024), 256, 0, stream>>>(Wih1, Whh1, W1hi, W1lo);
  pack_k<2><<<dim3(512), 256, 0, stream>>>(Wa, Wc, WAhi, WAlo);

  for (int t = 0; t < NSTEP; ++t) {
    const u16* ahphi = t ? (AHhi + (size_t)(t-1)*BATCH*HID) : zahhi;
    const u16* ahplo = t ? (AHlo + (size_t)(t-1)*BATCH*HID) : zahlo;
    const u16* h0phi = (t & 1) ? h0Bhi : h0Ahi;
    const u16* h0plo = (t & 1) ? h0Blo : h0Alo;
    u16* h0chi = (t & 1) ? h0Ahi : h0Bhi;
    u16* h0clo = (t & 1) ? h0Alo : h0Blo;
    const u16* h1phi = (t & 1) ? h1Bhi : h1Ahi;
    const u16* h1plo = (t & 1) ? h1Blo : h1Alo;
    u16* h1chi = (t & 1) ? h1Ahi : h1Bhi;
    u16* h1clo = (t & 1) ? h1Alo : h1Blo;

    { // L1: gates0 + cell0.  X = [ah_{t-1} | h0_{t-1}], W = [Wih0mid | Whh0]
      GKM p = {};
      p.Xahi = ahphi; p.Xalo = ahplo; p.Xbhi = h0phi; p.Xblo = h0plo;
      p.Whi = W0hi; p.Wlo = W0lo;
      p.bsum = bsum0; p.gembt = Gemb + (size_t)t*BATCH*G4;
      p.c = c0; p.hhi = h0chi; p.hlo = h0clo;
      gates_mfma_k<1><<<dim3(128), 256, 0, stream>>>(p);
    }
    { // L2: gates1 + cell1.  X = [h0_t | h1_{t-1}], W = [Wih1 | Whh1]
      GKM p = {};
      p.Xahi = h0chi; p.Xalo = h0clo; p.Xbhi = h1phi; p.Xblo = h1plo;
      p.Whi = W1hi; p.Wlo = W1lo;
      p.bsum = bsum1; p.gembt = nullptr;
      p.c = c1v; p.hhi = h1chi; p.hlo = h1clo;
      gates_mfma_k<0><<<dim3(128), 256, 0, stream>>>(p);
    }
    { // L3: Pq = h1_t · [Wa1;Wc1]^T
      PKM p; p.Xhi = h1chi; p.Xlo = h1clo; p.Whi = WAhi; p.Wlo = WAlo; p.Pq = Pq;
      proj_mfma_k<<<dim3(64), 256, 0, stream>>>(p);
    }
    { // L4: attention -> AH[t] (bf16 hi/lo)
      AKM p; p.Pq = Pq; p.PreAC = PreAC; p.va = va; p.bc = bc;
      p.AHthi = AHhi + (size_t)t*BATCH*HID;
      p.AHtlo = AHlo + (size_t)t*BATCH*HID;
      attn_k<<<dim3(BATCH), 1024, 0, stream>>>(p);
    }
  }

  // epilogue: Wo split (overlays loop scratch), batched MFMA logits, log-softmax+argmax
  cvt_k<<<dim3(4096), 256, 0, stream>>>(Wo, Wohi, Wolo, VOCAB*1024);
  {
    LM p; p.Ahi = AHhi; p.Alo = AHlo; p.Bhi = Wohi; p.Blo = Wolo;
    p.bo = bo; p.out = out;
    logits_mfma<<<dim3(32, VOCAB/128), 256, 0, stream>>>(p);
  }
  lsm_k<<<dim3(BATCH, NSTEP), 256, 0, stream>>>(out, words);
}